// Round 1
// baseline (3093.500 us; speedup 1.0000x reference)
//
#include <hip/hip_runtime.h>
#include <hip/hip_bf16.h>
#include <math.h>

#define NND 50000
#define HD  128
#define NE  800000

// ---------------- degree ----------------
__global__ __launch_bounds__(256) void k_deg(const int* __restrict__ col, int* __restrict__ deg) {
  int i = blockIdx.x * 256 + threadIdx.x;
  if (i < NE) atomicAdd(&deg[col[i]], 1);
}

__global__ __launch_bounds__(256) void k_dinv(const int* __restrict__ deg, float* __restrict__ dinv) {
  int v = blockIdx.x * 256 + threadIdx.x;
  if (v < NND) dinv[v] = rsqrtf((float)(deg[v] + 1));  // +1 self-loop; always > 0
}

// ---------------- dense GEMM: OUT[r, ooff + c] = sum_k X[r][k] * W[k*128+c] ----------------
// X: [NND][128] row-major. W: [128][128] row-major. 32 rows/block, 256 threads.
__global__ __launch_bounds__(256) void k_gemm(const float* __restrict__ X, const float* __restrict__ W,
                                              float* __restrict__ OUT, int ostride, int ooff) {
  __shared__ __align__(16) float Wl[128 * 128];   // 64 KB
  __shared__ __align__(16) float Xl[32 * 128];    // 16 KB
  int tid = threadIdx.x;
  // stage W (float4)
  {
    const float4* W4 = (const float4*)W;
    float4* Wl4 = (float4*)Wl;
    #pragma unroll
    for (int i = 0; i < 16; ++i) Wl4[tid + i * 256] = W4[tid + i * 256];
  }
  int r0 = blockIdx.x * 32;
  int nr = min(32, NND - r0);
  {
    const float4* X4 = (const float4*)X;
    float4* Xl4 = (float4*)Xl;
    #pragma unroll
    for (int i = 0; i < 4; ++i) {
      int idx = tid + i * 256;            // < 1024 float4 = 32 rows
      int r = idx >> 5;
      float4 z = make_float4(0.f, 0.f, 0.f, 0.f);
      Xl4[idx] = (r < nr) ? X4[r0 * 32 + idx] : z;
    }
  }
  __syncthreads();
  int c = tid & 127, rh = tid >> 7;       // rh=0: rows 0-15, rh=1: rows 16-31
  float acc[16];
  #pragma unroll
  for (int j = 0; j < 16; ++j) acc[j] = 0.f;
  const float4* Xl4 = (const float4*)Xl;
  for (int k = 0; k < 128; k += 4) {
    float w0 = Wl[(k + 0) * 128 + c];
    float w1 = Wl[(k + 1) * 128 + c];
    float w2 = Wl[(k + 2) * 128 + c];
    float w3 = Wl[(k + 3) * 128 + c];
    #pragma unroll
    for (int j = 0; j < 16; ++j) {
      float4 xv = Xl4[((rh * 16 + j) * 128 + k) >> 2];
      acc[j] = fmaf(xv.x, w0, acc[j]);
      acc[j] = fmaf(xv.y, w1, acc[j]);
      acc[j] = fmaf(xv.z, w2, acc[j]);
      acc[j] = fmaf(xv.w, w3, acc[j]);
    }
  }
  #pragma unroll
  for (int j = 0; j < 16; ++j) {
    int r = rh * 16 + j;
    if (r < nr) OUT[(long long)(r0 + r) * ostride + ooff + c] = acc[j];
  }
}

// ---------------- edge scatter: A[col] += T[row] * dinv[row]*dinv[col] ----------------
// one float4 per thread; 32 threads per edge
__global__ __launch_bounds__(256) void k_scatter(const int* __restrict__ row, const int* __restrict__ col,
                                                 const float* __restrict__ dinv, const float4* __restrict__ T4,
                                                 float* __restrict__ A) {
  int i = blockIdx.x * 256 + threadIdx.x;     // over NE*32
  if (i >= NE * 32) return;
  int e = i >> 5, q = i & 31;
  int r = row[e], cd = col[e];
  float nrm = dinv[r] * dinv[cd];
  float4 v = T4[r * 32 + q];
  float* dst = A + (long long)cd * 128 + q * 4;
  unsafeAtomicAdd(dst + 0, v.x * nrm);
  unsafeAtomicAdd(dst + 1, v.y * nrm);
  unsafeAtomicAdd(dst + 2, v.z * nrm);
  unsafeAtomicAdd(dst + 3, v.w * nrm);
}

// ---------------- self-loop + bias + relu: A = relu(A + T*dinv^2 + b) ----------------
__global__ __launch_bounds__(256) void k_finish(const float4* __restrict__ T4, float4* __restrict__ A4,
                                                const float* __restrict__ dinv, const float* __restrict__ bias) {
  int i = blockIdx.x * 256 + threadIdx.x;     // over NND*32
  if (i >= NND * 32) return;
  int v = i >> 5, q = i & 31;
  float s = dinv[v]; s = s * s;
  float4 t = T4[i], a = A4[i];
  float4 b = ((const float4*)bias)[q];
  a.x = fmaxf(a.x + t.x * s + b.x, 0.f);
  a.y = fmaxf(a.y + t.y * s + b.y, 0.f);
  a.z = fmaxf(a.z + t.z * s + b.z, 0.f);
  a.w = fmaxf(a.w + t.w * s + b.w, 0.f);
  A4[i] = a;
}

// ---------------- edge head: p = sigmoid( sum_c relu(U[row,c]+V[col,c]+be1[c]) * We2[c] + be2 )
// UV: [NND][256] (U = cols 0..127, V = cols 128..255). 32 lanes per edge, 8 edges/block.
__global__ __launch_bounds__(256) void k_edge(const int* __restrict__ row, const int* __restrict__ col,
                                              const float4* __restrict__ UV4, const float* __restrict__ be1,
                                              const float* __restrict__ We2, const float* __restrict__ be2,
                                              float* __restrict__ out) {
  int t = blockIdx.x * 256 + threadIdx.x;
  int e = t >> 5;
  if (e >= NE) return;
  int cb = t & 31;
  int r = row[e], c = col[e];
  float4 u = UV4[r * 64 + cb];
  float4 v = UV4[c * 64 + 32 + cb];
  float4 b = ((const float4*)be1)[cb];
  float4 w2 = ((const float4*)We2)[cb];
  float p = fmaxf(u.x + v.x + b.x, 0.f) * w2.x
          + fmaxf(u.y + v.y + b.y, 0.f) * w2.y
          + fmaxf(u.z + v.z + b.z, 0.f) * w2.z
          + fmaxf(u.w + v.w + b.w, 0.f) * w2.w;
  #pragma unroll
  for (int off = 16; off; off >>= 1) p += __shfl_xor(p, off);
  if (cb == 0) out[e] = 1.f / (1.f + __expf(-(p + be2[0])));
}

extern "C" void kernel_launch(void* const* d_in, const int* in_sizes, int n_in,
                              void* d_out, int out_size, void* d_ws, size_t ws_size,
                              hipStream_t stream) {
  const float* x   = (const float*)d_in[0];
  const int*   ei  = (const int*)d_in[1];
  const float* W1  = (const float*)d_in[2];
  const float* b1  = (const float*)d_in[3];
  const float* W2  = (const float*)d_in[4];
  const float* b2  = (const float*)d_in[5];
  const float* We1 = (const float*)d_in[6];
  const float* be1 = (const float*)d_in[7];
  const float* We2 = (const float*)d_in[8];
  const float* be2 = (const float*)d_in[9];
  float* out = (float*)d_out;

  const int* row = ei;
  const int* colp = ei + NE;

  // workspace layout (floats): deg(int)[50048] | dinv[50048] | T[6.4M] | A[6.4M] | UV[12.8M]
  if (ws_size < (size_t)25700096 * 4) return;
  int*   deg  = (int*)d_ws;
  float* dinv = (float*)d_ws + 50048;
  float* T    = (float*)d_ws + 100096;
  float* A    = (float*)d_ws + 6500096;
  float* UV   = (float*)d_ws + 12900096;

  hipMemsetAsync(deg, 0, NND * sizeof(int), stream);
  k_deg<<<(NE + 255) / 256, 256, 0, stream>>>(colp, deg);
  k_dinv<<<(NND + 255) / 256, 256, 0, stream>>>(deg, dinv);

  // ---- layer 1: T = x@W1; A = scatter(T) ; A = relu(A + T*dinv^2 + b1)
  k_gemm<<<(NND + 31) / 32, 256, 0, stream>>>(x, W1, T, 128, 0);
  hipMemsetAsync(A, 0, (size_t)NND * 128 * sizeof(float), stream);
  k_scatter<<<NE * 32 / 256, 256, 0, stream>>>(row, colp, dinv, (const float4*)T, A);
  k_finish<<<NND * 32 / 256 + 1, 256, 0, stream>>>((const float4*)T, (float4*)A, dinv, b1);

  // ---- layer 2: T = A@W2; A = scatter(T); A = relu(A + T*dinv^2 + b2)   (A ends as h2)
  k_gemm<<<(NND + 31) / 32, 256, 0, stream>>>(A, W2, T, 128, 0);
  hipMemsetAsync(A, 0, (size_t)NND * 128 * sizeof(float), stream);
  k_scatter<<<NE * 32 / 256, 256, 0, stream>>>(row, colp, dinv, (const float4*)T, A);
  k_finish<<<NND * 32 / 256 + 1, 256, 0, stream>>>((const float4*)T, (float4*)A, dinv, b2);

  // ---- edge head: UV[:, :128] = h2@We1_top ; UV[:, 128:] = h2@We1_bot ; then per-edge
  k_gemm<<<(NND + 31) / 32, 256, 0, stream>>>(A, We1, UV, 256, 0);
  k_gemm<<<(NND + 31) / 32, 256, 0, stream>>>(A, We1 + 128 * 128, UV, 256, 128);
  k_edge<<<NE * 32 / 256, 256, 0, stream>>>(row, colp, (const float4*)UV, be1, We2, be2, out);
}

// Round 2
// 602.855 us; speedup vs baseline: 5.1314x; 5.1314x over previous
//
#include <hip/hip_runtime.h>
#include <hip/hip_bf16.h>
#include <math.h>

#define NND 50000
#define HD  128
#define NE  800000

// ---------------- degree (in-degree over col) ----------------
__global__ __launch_bounds__(256) void k_deg(const int* __restrict__ col, int* __restrict__ deg) {
  int i = blockIdx.x * 256 + threadIdx.x;
  if (i < NE) atomicAdd(&deg[col[i]], 1);
}

__global__ __launch_bounds__(256) void k_dinv(const int* __restrict__ deg, float* __restrict__ dinv) {
  int v = blockIdx.x * 256 + threadIdx.x;
  if (v < NND) dinv[v] = rsqrtf((float)(deg[v] + 1));  // +1 self-loop; always > 0
}

// ---------------- exclusive scan of deg -> ptr[NND+1], cursor copy ----------------
// single block, 1024 threads, wave-shuffle scan (2 LDS syncs per 1024-chunk)
__global__ __launch_bounds__(1024) void k_scan(const int* __restrict__ deg, int* __restrict__ ptr,
                                               int* __restrict__ cursor) {
  __shared__ int wsum[16];
  __shared__ int carry;
  int tid = threadIdx.x, lane = tid & 63, wid = tid >> 6;
  if (tid == 0) carry = 0;
  __syncthreads();
  for (int base = 0; base < NND; base += 1024) {
    int v = base + tid;
    int d = (v < NND) ? deg[v] : 0;
    int x = d;
    #pragma unroll
    for (int off = 1; off < 64; off <<= 1) {
      int y = __shfl_up(x, off);
      if (lane >= off) x += y;
    }
    if (lane == 63) wsum[wid] = x;
    __syncthreads();
    if (tid < 16) {
      int w = wsum[tid];
      #pragma unroll
      for (int off = 1; off < 16; off <<= 1) {
        int y = __shfl_up(w, off);
        if (tid >= off) w += y;
      }
      wsum[tid] = w;  // inclusive over wave sums
    }
    __syncthreads();
    int boff = carry + (wid ? wsum[wid - 1] : 0);
    int excl = boff + x - d;
    if (v < NND) { ptr[v] = excl; cursor[v] = excl; }
    __syncthreads();
    if (tid == 0) carry += wsum[15];
    __syncthreads();
  }
  if (tid == 0) ptr[NND] = carry;
}

// ---------------- counting-sort placement: srow/seid grouped by col ----------------
__global__ __launch_bounds__(256) void k_place(const int* __restrict__ row, const int* __restrict__ col,
                                               int* __restrict__ cursor, int* __restrict__ srow,
                                               int* __restrict__ seid) {
  int e = blockIdx.x * 256 + threadIdx.x;
  if (e >= NE) return;
  int c = col[e];
  int slot = atomicAdd(&cursor[c], 1);
  srow[slot] = row[e];
  seid[slot] = e;
}

// ---------------- dense GEMM: OUT[r][c] = (sum_k X[r][k]*W[k][c]) * (scale?scale[r]:1) ----------------
__global__ __launch_bounds__(256) void k_gemm(const float* __restrict__ X, const float* __restrict__ W,
                                              float* __restrict__ OUT, const float* __restrict__ scale) {
  __shared__ __align__(16) float Wl[128 * 128];   // 64 KB
  __shared__ __align__(16) float Xl[32 * 128];    // 16 KB
  int tid = threadIdx.x;
  {
    const float4* W4 = (const float4*)W;
    float4* Wl4 = (float4*)Wl;
    #pragma unroll
    for (int i = 0; i < 16; ++i) Wl4[tid + i * 256] = W4[tid + i * 256];
  }
  int r0 = blockIdx.x * 32;
  int nr = min(32, NND - r0);
  {
    const float4* X4 = (const float4*)X;
    float4* Xl4 = (float4*)Xl;
    #pragma unroll
    for (int i = 0; i < 4; ++i) {
      int idx = tid + i * 256;
      int r = idx >> 5;
      float4 z = make_float4(0.f, 0.f, 0.f, 0.f);
      Xl4[idx] = (r < nr) ? X4[r0 * 32 + idx] : z;
    }
  }
  __syncthreads();
  int c = tid & 127, rh = tid >> 7;
  float acc[16];
  #pragma unroll
  for (int j = 0; j < 16; ++j) acc[j] = 0.f;
  const float4* Xl4 = (const float4*)Xl;
  for (int k = 0; k < 128; k += 4) {
    float w0 = Wl[(k + 0) * 128 + c];
    float w1 = Wl[(k + 1) * 128 + c];
    float w2 = Wl[(k + 2) * 128 + c];
    float w3 = Wl[(k + 3) * 128 + c];
    #pragma unroll
    for (int j = 0; j < 16; ++j) {
      float4 xv = Xl4[((rh * 16 + j) * 128 + k) >> 2];
      acc[j] = fmaf(xv.x, w0, acc[j]);
      acc[j] = fmaf(xv.y, w1, acc[j]);
      acc[j] = fmaf(xv.z, w2, acc[j]);
      acc[j] = fmaf(xv.w, w3, acc[j]);
    }
  }
  #pragma unroll
  for (int j = 0; j < 16; ++j) {
    int r = rh * 16 + j;
    if (r < nr) {
      float sc = scale ? scale[r0 + r] : 1.0f;
      OUT[(size_t)(r0 + r) * 128 + c] = acc[j] * sc;
    }
  }
}

// ---------------- gather-aggregate: H[v] = relu(dinv[v]*(Ts[v] + sum_{r in in(v)} Ts[r]) + b) ----------
// 32 lanes per node, one float4 per lane
__global__ __launch_bounds__(256) void k_gather(const int* __restrict__ ptr, const int* __restrict__ srow,
                                                const float* __restrict__ dinv, const float4* __restrict__ Ts4,
                                                float4* __restrict__ H4, const float* __restrict__ bias) {
  int t = blockIdx.x * 256 + threadIdx.x;
  int v = t >> 5; if (v >= NND) return;
  int q = t & 31;
  int p0 = ptr[v], p1 = ptr[v + 1];
  float4 acc = Ts4[(size_t)v * 32 + q];   // self-loop (Ts already scaled by dinv[src])
  for (int j = p0; j < p1; ++j) {
    int r = srow[j];
    float4 m = Ts4[(size_t)r * 32 + q];
    acc.x += m.x; acc.y += m.y; acc.z += m.z; acc.w += m.w;
  }
  float s = dinv[v];
  float4 b = ((const float4*)bias)[q];
  float4 o;
  o.x = fmaxf(fmaf(acc.x, s, b.x), 0.f);
  o.y = fmaxf(fmaf(acc.y, s, b.y), 0.f);
  o.z = fmaxf(fmaf(acc.z, s, b.z), 0.f);
  o.w = fmaxf(fmaf(acc.w, s, b.w), 0.f);
  H4[(size_t)v * 32 + q] = o;
}

// ---------------- edge head, CSR order: V[c] staged in regs, gather U[row] --------------------------
// p = sigmoid( sum_c relu(U[row]+V[col]+be1) . We2 + be2 ), written to out[orig edge id]
__global__ __launch_bounds__(256) void k_edge_csr(const int* __restrict__ ptr, const int* __restrict__ srow,
                                                  const int* __restrict__ seid,
                                                  const float4* __restrict__ U4, const float4* __restrict__ V4,
                                                  const float* __restrict__ be1, const float* __restrict__ We2,
                                                  const float* __restrict__ be2, float* __restrict__ out) {
  int t = blockIdx.x * 256 + threadIdx.x;
  int c = t >> 5; if (c >= NND) return;
  int q = t & 31;
  int p0 = ptr[c], p1 = ptr[c + 1];
  if (p0 == p1) return;
  float4 vv = V4[(size_t)c * 32 + q];
  float4 b = ((const float4*)be1)[q];
  vv.x += b.x; vv.y += b.y; vv.z += b.z; vv.w += b.w;
  float4 w2 = ((const float4*)We2)[q];
  float bias2 = be2[0];
  for (int j = p0; j < p1; ++j) {
    int r = srow[j];
    float4 u = U4[(size_t)r * 32 + q];
    float p = fmaxf(u.x + vv.x, 0.f) * w2.x
            + fmaxf(u.y + vv.y, 0.f) * w2.y
            + fmaxf(u.z + vv.z, 0.f) * w2.z
            + fmaxf(u.w + vv.w, 0.f) * w2.w;
    #pragma unroll
    for (int off = 16; off; off >>= 1) p += __shfl_xor(p, off);
    if (q == 0) out[seid[j]] = 1.f / (1.f + __expf(-(p + bias2)));
  }
}

extern "C" void kernel_launch(void* const* d_in, const int* in_sizes, int n_in,
                              void* d_out, int out_size, void* d_ws, size_t ws_size,
                              hipStream_t stream) {
  const float* x   = (const float*)d_in[0];
  const int*   ei  = (const int*)d_in[1];
  const float* W1  = (const float*)d_in[2];
  const float* b1  = (const float*)d_in[3];
  const float* W2  = (const float*)d_in[4];
  const float* b2  = (const float*)d_in[5];
  const float* We1 = (const float*)d_in[6];
  const float* be1 = (const float*)d_in[7];
  const float* We2 = (const float*)d_in[8];
  const float* be2 = (const float*)d_in[9];
  float* out = (float*)d_out;

  const int* row  = ei;
  const int* colp = ei + NE;

  // ws layout (4B units):
  // deg[0,50048) ptr[50048,100352) cursor[100352,150400) dinv[150400,200448)
  // srow[200448,1000448) seid[1000448,1800448)
  // Ts/U [1800448, +6.4M) | H [8200448, +6.4M) | V [14600448, +6.4M)  total 21000448
  if (ws_size < (size_t)21000448 * 4) return;
  int*   deg    = (int*)d_ws;
  int*   ptr    = (int*)d_ws + 50048;
  int*   cursor = (int*)d_ws + 100352;
  float* dinv   = (float*)d_ws + 150400;
  int*   srow   = (int*)d_ws + 200448;
  int*   seid   = (int*)d_ws + 1000448;
  float* Ts     = (float*)d_ws + 1800448;   // also reused as U
  float* H      = (float*)d_ws + 8200448;
  float* V      = (float*)d_ws + 14600448;

  hipMemsetAsync(deg, 0, NND * sizeof(int), stream);
  k_deg  <<<(NE + 255) / 256, 256, 0, stream>>>(colp, deg);
  k_dinv <<<(NND + 255) / 256, 256, 0, stream>>>(deg, dinv);
  k_scan <<<1, 1024, 0, stream>>>(deg, ptr, cursor);
  k_place<<<(NE + 255) / 256, 256, 0, stream>>>(row, colp, cursor, srow, seid);

  int gemm_grid = (NND + 31) / 32;
  int node_grid = (NND * 32 + 255) / 256;

  // layer 1: Ts = (x@W1)*dinv ; H = relu(dinv*(Ts_self + gather) + b1)
  k_gemm  <<<gemm_grid, 256, 0, stream>>>(x, W1, Ts, dinv);
  k_gather<<<node_grid, 256, 0, stream>>>(ptr, srow, dinv, (const float4*)Ts, (float4*)H, b1);

  // layer 2: Ts = (H@W2)*dinv ; H = relu(dinv*(Ts_self + gather) + b2)
  k_gemm  <<<gemm_grid, 256, 0, stream>>>(H, W2, Ts, dinv);
  k_gather<<<node_grid, 256, 0, stream>>>(ptr, srow, dinv, (const float4*)Ts, (float4*)H, b2);

  // edge head: U = H@We1_top ; V = H@We1_bot ; per-edge in CSR order
  k_gemm<<<gemm_grid, 256, 0, stream>>>(H, We1, Ts /*U*/, nullptr);
  k_gemm<<<gemm_grid, 256, 0, stream>>>(H, We1 + 128 * 128, V, nullptr);
  k_edge_csr<<<node_grid, 256, 0, stream>>>(ptr, srow, seid, (const float4*)Ts, (const float4*)V,
                                            be1, We2, be2, out);
}

// Round 3
// 463.487 us; speedup vs baseline: 6.6744x; 1.3007x over previous
//
#include <hip/hip_runtime.h>
#include <math.h>

#define NND 50000
#define HD  128
#define NE  800000
#define SCAN_B 196   // ceil(NND/256)

typedef unsigned short u16;
typedef unsigned int   u32;

__device__ __forceinline__ float bf2f(u32 u) {
  union { u32 i; float f; } v; v.i = u << 16; return v.f;
}
__device__ __forceinline__ u16 f2bf(float f) {
  union { float f; u32 i; } v; v.f = f;
  return (u16)((v.i + 0x7FFFu + ((v.i >> 16) & 1u)) >> 16);
}
__device__ __forceinline__ float4 unpack4(uint2 m) {
  float4 r;
  r.x = bf2f(m.x & 0xFFFFu); r.y = bf2f(m.x >> 16);
  r.z = bf2f(m.y & 0xFFFFu); r.w = bf2f(m.y >> 16);
  return r;
}

// ---------------- degree (in-degree over col) ----------------
__global__ __launch_bounds__(256) void k_deg(const int* __restrict__ col, int* __restrict__ deg) {
  int i = blockIdx.x * 256 + threadIdx.x;
  if (i < NE) atomicAdd(&deg[col[i]], 1);
}

// ---------------- hierarchical scan ----------------
__global__ __launch_bounds__(256) void k_scan1(const int* __restrict__ deg, int* __restrict__ ptr,
                                               int* __restrict__ bsum) {
  __shared__ int ws[4];
  int tid = threadIdx.x, lane = tid & 63, wid = tid >> 6;
  int i = blockIdx.x * 256 + tid;
  int d = (i < NND) ? deg[i] : 0;
  int x = d;
  #pragma unroll
  for (int off = 1; off < 64; off <<= 1) {
    int y = __shfl_up(x, off);
    if (lane >= off) x += y;
  }
  if (lane == 63) ws[wid] = x;
  __syncthreads();
  int woff = 0;
  for (int w = 0; w < wid; ++w) woff += ws[w];
  if (i < NND) ptr[i] = woff + x - d;
  if (tid == 255) bsum[blockIdx.x] = woff + x;
}

__global__ __launch_bounds__(256) void k_scan2(const int* __restrict__ bsum, int* __restrict__ boff,
                                               int* __restrict__ ptr) {
  __shared__ int ws[4];
  int tid = threadIdx.x, lane = tid & 63, wid = tid >> 6;
  int d = (tid < SCAN_B) ? bsum[tid] : 0;
  int x = d;
  #pragma unroll
  for (int off = 1; off < 64; off <<= 1) {
    int y = __shfl_up(x, off);
    if (lane >= off) x += y;
  }
  if (lane == 63) ws[wid] = x;
  __syncthreads();
  int woff = 0;
  for (int w = 0; w < wid; ++w) woff += ws[w];
  if (tid < SCAN_B) boff[tid] = woff + x - d;
  if (tid == 0) ptr[NND] = NE;
}

__global__ __launch_bounds__(256) void k_scan3(const int* __restrict__ deg, const int* __restrict__ boff,
                                               int* __restrict__ ptr, int* __restrict__ cursor,
                                               float* __restrict__ dinv) {
  int i = blockIdx.x * 256 + threadIdx.x;
  if (i >= NND) return;
  int p = ptr[i] + boff[i >> 8];
  ptr[i] = p;
  cursor[i] = p;
  dinv[i] = rsqrtf((float)(deg[i] + 1));
}

// ---------------- counting-sort placement: (row, eid) pairs grouped by col ----------------
__global__ __launch_bounds__(256) void k_place(const int* __restrict__ row, const int* __restrict__ col,
                                               int* __restrict__ cursor, uint2* __restrict__ sre) {
  int e = blockIdx.x * 256 + threadIdx.x;
  if (e >= NE) return;
  int c = col[e];
  int slot = atomicAdd(&cursor[c], 1);
  sre[slot] = make_uint2((u32)row[e], (u32)e);
}

// ---------------- fp32 x -> bf16 ----------------
__global__ __launch_bounds__(256) void k_cast(const float4* __restrict__ x, uint2* __restrict__ xb) {
  int i = blockIdx.x * 256 + threadIdx.x;
  if (i >= NND * 32) return;
  float4 v = x[i];
  uint2 o;
  o.x = (u32)f2bf(v.x) | ((u32)f2bf(v.y) << 16);
  o.y = (u32)f2bf(v.z) | ((u32)f2bf(v.w) << 16);
  xb[i] = o;
}

// ---------------- GEMM: OUT[r][c] = bf16( (sum_k X[r][k]*W[k][c]) * (scale?scale[r]:1) ) ----------
// X bf16 [NND][128], W fp32 [128][128], OUT bf16. 32 rows/block, 256 threads, 8x2 reg tile.
__global__ __launch_bounds__(256, 2) void k_gemm(const u16* __restrict__ X, const float* __restrict__ W,
                                                 u16* __restrict__ OUT, const float* __restrict__ scale) {
  __shared__ __align__(16) float Wl[128 * 128];   // 64 KB
  __shared__ __align__(16) float Xl[32 * 128];    // 16 KB
  int tid = threadIdx.x;
  {
    const float4* W4 = (const float4*)W;
    float4* Wl4 = (float4*)Wl;
    #pragma unroll
    for (int i = 0; i < 16; ++i) Wl4[tid + i * 256] = W4[tid + i * 256];
  }
  int r0 = blockIdx.x * 32;
  int nr = min(32, NND - r0);
  {
    const uint4* X16 = (const uint4*)(X + (size_t)r0 * 128);
    #pragma unroll
    for (int i = 0; i < 2; ++i) {
      int idx = tid + i * 256;            // 512 chunks of 8 elems
      int rr = idx >> 4;
      uint4 m = make_uint4(0, 0, 0, 0);
      if (rr < nr) m = X16[idx];
      int base = rr * 128 + (idx & 15) * 8;
      Xl[base + 0] = bf2f(m.x & 0xFFFFu); Xl[base + 1] = bf2f(m.x >> 16);
      Xl[base + 2] = bf2f(m.y & 0xFFFFu); Xl[base + 3] = bf2f(m.y >> 16);
      Xl[base + 4] = bf2f(m.z & 0xFFFFu); Xl[base + 5] = bf2f(m.z >> 16);
      Xl[base + 6] = bf2f(m.w & 0xFFFFu); Xl[base + 7] = bf2f(m.w >> 16);
    }
  }
  __syncthreads();
  int c2 = (tid & 63) * 2, rg = tid >> 6;
  float acc[8][2];
  #pragma unroll
  for (int j = 0; j < 8; ++j) { acc[j][0] = 0.f; acc[j][1] = 0.f; }
  const float4* Xl4 = (const float4*)Xl;
  for (int k0 = 0; k0 < 128; k0 += 4) {
    float2 w0 = *(const float2*)&Wl[(k0 + 0) * 128 + c2];
    float2 w1 = *(const float2*)&Wl[(k0 + 1) * 128 + c2];
    float2 w2 = *(const float2*)&Wl[(k0 + 2) * 128 + c2];
    float2 w3 = *(const float2*)&Wl[(k0 + 3) * 128 + c2];
    #pragma unroll
    for (int j = 0; j < 8; ++j) {
      float4 xv = Xl4[((rg * 8 + j) * 128 + k0) >> 2];
      acc[j][0] = fmaf(xv.x, w0.x, acc[j][0]); acc[j][1] = fmaf(xv.x, w0.y, acc[j][1]);
      acc[j][0] = fmaf(xv.y, w1.x, acc[j][0]); acc[j][1] = fmaf(xv.y, w1.y, acc[j][1]);
      acc[j][0] = fmaf(xv.z, w2.x, acc[j][0]); acc[j][1] = fmaf(xv.z, w2.y, acc[j][1]);
      acc[j][0] = fmaf(xv.w, w3.x, acc[j][0]); acc[j][1] = fmaf(xv.w, w3.y, acc[j][1]);
    }
  }
  #pragma unroll
  for (int j = 0; j < 8; ++j) {
    int lr = rg * 8 + j;
    if (lr < nr) {
      int r = r0 + lr;
      float sc = scale ? scale[r] : 1.0f;
      u32 pk = (u32)f2bf(acc[j][0] * sc) | ((u32)f2bf(acc[j][1] * sc) << 16);
      *(u32*)(OUT + (size_t)r * 128 + c2) = pk;
    }
  }
}

// ---------------- gather-aggregate: H[v] = bf16(relu(dinv[v]*(Ts[v] + sum_in Ts[r]) + b)) ----------
// 32 lanes per node, 4 elems (8B) per lane
__global__ __launch_bounds__(256) void k_gather(const int* __restrict__ ptr, const uint2* __restrict__ sre,
                                                const float* __restrict__ dinv, const u16* __restrict__ Ts,
                                                u16* __restrict__ H, const float* __restrict__ bias) {
  int t = blockIdx.x * 256 + threadIdx.x;
  int v = t >> 5; if (v >= NND) return;
  int q = t & 31;
  int p0 = ptr[v], p1 = ptr[v + 1];
  const uint2* T2 = (const uint2*)Ts;
  float4 acc = unpack4(T2[(size_t)v * 32 + q]);   // self-loop (Ts pre-scaled by dinv[src])
  for (int j = p0; j < p1; ++j) {
    int r = (int)sre[j].x;
    float4 m = unpack4(T2[(size_t)r * 32 + q]);
    acc.x += m.x; acc.y += m.y; acc.z += m.z; acc.w += m.w;
  }
  float s = dinv[v];
  float4 b = ((const float4*)bias)[q];
  uint2 o;
  float o0 = fmaxf(fmaf(acc.x, s, b.x), 0.f);
  float o1 = fmaxf(fmaf(acc.y, s, b.y), 0.f);
  float o2 = fmaxf(fmaf(acc.z, s, b.z), 0.f);
  float o3 = fmaxf(fmaf(acc.w, s, b.w), 0.f);
  o.x = (u32)f2bf(o0) | ((u32)f2bf(o1) << 16);
  o.y = (u32)f2bf(o2) | ((u32)f2bf(o3) << 16);
  ((uint2*)H)[(size_t)v * 32 + q] = o;
}

// ---------------- edge head, CSR order ----------------
__global__ __launch_bounds__(256) void k_edge(const int* __restrict__ ptr, const uint2* __restrict__ sre,
                                              const u16* __restrict__ U, const u16* __restrict__ V,
                                              const float* __restrict__ be1, const float* __restrict__ We2,
                                              const float* __restrict__ be2, float* __restrict__ out) {
  int t = blockIdx.x * 256 + threadIdx.x;
  int c = t >> 5; if (c >= NND) return;
  int q = t & 31;
  int p0 = ptr[c], p1 = ptr[c + 1];
  if (p0 == p1) return;
  const uint2* U2 = (const uint2*)U;
  const uint2* V2 = (const uint2*)V;
  float4 vv = unpack4(V2[(size_t)c * 32 + q]);
  float4 b = ((const float4*)be1)[q];
  vv.x += b.x; vv.y += b.y; vv.z += b.z; vv.w += b.w;
  float4 w2 = ((const float4*)We2)[q];
  float bias2 = be2[0];
  for (int j = p0; j < p1; ++j) {
    uint2 e = sre[j];
    float4 u = unpack4(U2[(size_t)e.x * 32 + q]);
    float p = fmaxf(u.x + vv.x, 0.f) * w2.x
            + fmaxf(u.y + vv.y, 0.f) * w2.y
            + fmaxf(u.z + vv.z, 0.f) * w2.z
            + fmaxf(u.w + vv.w, 0.f) * w2.w;
    #pragma unroll
    for (int off = 16; off; off >>= 1) p += __shfl_xor(p, off);
    if (q == 0) out[e.y] = 1.f / (1.f + __expf(-(p + bias2)));
  }
}

extern "C" void kernel_launch(void* const* d_in, const int* in_sizes, int n_in,
                              void* d_out, int out_size, void* d_ws, size_t ws_size,
                              hipStream_t stream) {
  const float* x   = (const float*)d_in[0];
  const int*   ei  = (const int*)d_in[1];
  const float* W1  = (const float*)d_in[2];
  const float* b1  = (const float*)d_in[3];
  const float* W2  = (const float*)d_in[4];
  const float* b2  = (const float*)d_in[5];
  const float* We1 = (const float*)d_in[6];
  const float* be1 = (const float*)d_in[7];
  const float* We2 = (const float*)d_in[8];
  const float* be2 = (const float*)d_in[9];
  float* out = (float*)d_out;

  const int* row  = ei;
  const int* colp = ei + NE;

  // ws layout (4B units):
  // deg[0,50048) ptr[50048,100352) cursor[100352,150400) dinv[150400,200448)
  // bsum[200448,200704) boff[200704,200960) sre[200960,1800960)
  // xb[1800960,+3.2M) Ts[5000960,+3.2M) H[8200960,+3.2M) U[11400960,+3.2M) V[14600960,+3.2M)
  if (ws_size < (size_t)17800960 * 4) return;
  int*   deg    = (int*)d_ws;
  int*   ptr    = (int*)d_ws + 50048;
  int*   cursor = (int*)d_ws + 100352;
  float* dinv   = (float*)d_ws + 150400;
  int*   bsum   = (int*)d_ws + 200448;
  int*   boff   = (int*)d_ws + 200704;
  uint2* sre    = (uint2*)((int*)d_ws + 200960);
  u16*   xb     = (u16*)((int*)d_ws + 1800960);
  u16*   Ts     = (u16*)((int*)d_ws + 5000960);   // reused as U
  u16*   H      = (u16*)((int*)d_ws + 8200960);
  u16*   U      = (u16*)((int*)d_ws + 11400960);
  u16*   V      = (u16*)((int*)d_ws + 14600960);

  hipMemsetAsync(deg, 0, NND * sizeof(int), stream);
  k_deg  <<<(NE + 255) / 256, 256, 0, stream>>>(colp, deg);
  k_scan1<<<SCAN_B, 256, 0, stream>>>(deg, ptr, bsum);
  k_scan2<<<1, 256, 0, stream>>>(bsum, boff, ptr);
  k_scan3<<<SCAN_B, 256, 0, stream>>>(deg, boff, ptr, cursor, dinv);
  k_place<<<(NE + 255) / 256, 256, 0, stream>>>(row, colp, cursor, sre);
  k_cast <<<(NND * 32 + 255) / 256, 256, 0, stream>>>((const float4*)x, (uint2*)xb);

  int gemm_grid = (NND + 31) / 32;
  int node_grid = (NND * 32 + 255) / 256;

  // layer 1: Ts = bf16((xb@W1)*dinv) ; H = relu(dinv*(Ts_self + gather) + b1)
  k_gemm  <<<gemm_grid, 256, 0, stream>>>(xb, W1, Ts, dinv);
  k_gather<<<node_grid, 256, 0, stream>>>(ptr, sre, dinv, Ts, H, b1);

  // layer 2
  k_gemm  <<<gemm_grid, 256, 0, stream>>>(H, W2, Ts, dinv);
  k_gather<<<node_grid, 256, 0, stream>>>(ptr, sre, dinv, Ts, H, b2);

  // edge head
  k_gemm<<<gemm_grid, 256, 0, stream>>>(H, We1, U, nullptr);
  k_gemm<<<gemm_grid, 256, 0, stream>>>(H, We1 + 128 * 128, V, nullptr);
  k_edge<<<node_grid, 256, 0, stream>>>(ptr, sre, U, V, be1, We2, be2, out);
}

// Round 4
// 415.971 us; speedup vs baseline: 7.4368x; 1.1142x over previous
//
#include <hip/hip_runtime.h>
#include <math.h>

#define NND 50000
#define HD  128
#define NE  800000
#define SCAN_B 196   // ceil(NND/256)

typedef unsigned short u16;
typedef unsigned int   u32;

__device__ __forceinline__ float bf2f(u32 u) {
  union { u32 i; float f; } v; v.i = u << 16; return v.f;
}
__device__ __forceinline__ u16 f2bf(float f) {
  union { float f; u32 i; } v; v.f = f;
  return (u16)((v.i + 0x7FFFu + ((v.i >> 16) & 1u)) >> 16);
}
__device__ __forceinline__ float4 unpack4(uint2 m) {
  float4 r;
  r.x = bf2f(m.x & 0xFFFFu); r.y = bf2f(m.x >> 16);
  r.z = bf2f(m.y & 0xFFFFu); r.w = bf2f(m.y >> 16);
  return r;
}

// ---------------- degree (in-degree over col) ----------------
__global__ __launch_bounds__(256) void k_deg(const int* __restrict__ col, int* __restrict__ deg) {
  int i = blockIdx.x * 256 + threadIdx.x;
  if (i < NE) atomicAdd(&deg[col[i]], 1);
}

// ---------------- hierarchical scan ----------------
__global__ __launch_bounds__(256) void k_scan1(const int* __restrict__ deg, int* __restrict__ ptr,
                                               int* __restrict__ bsum) {
  __shared__ int ws[4];
  int tid = threadIdx.x, lane = tid & 63, wid = tid >> 6;
  int i = blockIdx.x * 256 + tid;
  int d = (i < NND) ? deg[i] : 0;
  int x = d;
  #pragma unroll
  for (int off = 1; off < 64; off <<= 1) {
    int y = __shfl_up(x, off);
    if (lane >= off) x += y;
  }
  if (lane == 63) ws[wid] = x;
  __syncthreads();
  int woff = 0;
  for (int w = 0; w < wid; ++w) woff += ws[w];
  if (i < NND) ptr[i] = woff + x - d;
  if (tid == 255) bsum[blockIdx.x] = woff + x;
}

__global__ __launch_bounds__(256) void k_scan2(const int* __restrict__ bsum, int* __restrict__ boff,
                                               int* __restrict__ ptr) {
  __shared__ int ws[4];
  int tid = threadIdx.x, lane = tid & 63, wid = tid >> 6;
  int d = (tid < SCAN_B) ? bsum[tid] : 0;
  int x = d;
  #pragma unroll
  for (int off = 1; off < 64; off <<= 1) {
    int y = __shfl_up(x, off);
    if (lane >= off) x += y;
  }
  if (lane == 63) ws[wid] = x;
  __syncthreads();
  int woff = 0;
  for (int w = 0; w < wid; ++w) woff += ws[w];
  if (tid < SCAN_B) boff[tid] = woff + x - d;
  if (tid == 0) ptr[NND] = NE;
}

__global__ __launch_bounds__(256) void k_scan3(const int* __restrict__ deg, const int* __restrict__ boff,
                                               int* __restrict__ ptr, int* __restrict__ cursor,
                                               float* __restrict__ dinv) {
  int i = blockIdx.x * 256 + threadIdx.x;
  if (i >= NND) return;
  int p = ptr[i] + boff[i >> 8];
  ptr[i] = p;
  cursor[i] = p;
  dinv[i] = rsqrtf((float)(deg[i] + 1));
}

// ---------------- counting-sort placement: (row, eid) pairs grouped by col ----------------
__global__ __launch_bounds__(256) void k_place(const int* __restrict__ row, const int* __restrict__ col,
                                               int* __restrict__ cursor, uint2* __restrict__ sre) {
  int e = blockIdx.x * 256 + threadIdx.x;
  if (e >= NE) return;
  int c = col[e];
  int slot = atomicAdd(&cursor[c], 1);
  sre[slot] = make_uint2((u32)row[e], (u32)e);
}

// ---------------- fp32 x -> bf16 ----------------
__global__ __launch_bounds__(256) void k_cast(const float4* __restrict__ x, uint2* __restrict__ xb) {
  int i = blockIdx.x * 256 + threadIdx.x;
  if (i >= NND * 32) return;
  float4 v = x[i];
  uint2 o;
  o.x = (u32)f2bf(v.x) | ((u32)f2bf(v.y) << 16);
  o.y = (u32)f2bf(v.z) | ((u32)f2bf(v.w) << 16);
  xb[i] = o;
}

// ---------------- GEMM: OUT[r][c] = bf16( (sum_k X[r][k]*W[k][c]) * (scale?scale[r]:1) ) ----------
// X bf16 [NND][128], W fp32 [128][128], OUT bf16. 32 rows/block, 256 threads, 8x2 reg tile.
__global__ __launch_bounds__(256, 2) void k_gemm(const u16* __restrict__ X, const float* __restrict__ W,
                                                 u16* __restrict__ OUT, const float* __restrict__ scale) {
  __shared__ __align__(16) float Wl[128 * 128];   // 64 KB
  __shared__ __align__(16) float Xl[32 * 128];    // 16 KB
  int tid = threadIdx.x;
  {
    const float4* W4 = (const float4*)W;
    float4* Wl4 = (float4*)Wl;
    #pragma unroll
    for (int i = 0; i < 16; ++i) Wl4[tid + i * 256] = W4[tid + i * 256];
  }
  int r0 = blockIdx.x * 32;
  int nr = min(32, NND - r0);
  {
    const uint4* X16 = (const uint4*)(X + (size_t)r0 * 128);
    #pragma unroll
    for (int i = 0; i < 2; ++i) {
      int idx = tid + i * 256;            // 512 chunks of 8 elems
      int rr = idx >> 4;
      uint4 m = make_uint4(0, 0, 0, 0);
      if (rr < nr) m = X16[idx];
      int base = rr * 128 + (idx & 15) * 8;
      Xl[base + 0] = bf2f(m.x & 0xFFFFu); Xl[base + 1] = bf2f(m.x >> 16);
      Xl[base + 2] = bf2f(m.y & 0xFFFFu); Xl[base + 3] = bf2f(m.y >> 16);
      Xl[base + 4] = bf2f(m.z & 0xFFFFu); Xl[base + 5] = bf2f(m.z >> 16);
      Xl[base + 6] = bf2f(m.w & 0xFFFFu); Xl[base + 7] = bf2f(m.w >> 16);
    }
  }
  __syncthreads();
  int c2 = (tid & 63) * 2, rg = tid >> 6;
  float acc[8][2];
  #pragma unroll
  for (int j = 0; j < 8; ++j) { acc[j][0] = 0.f; acc[j][1] = 0.f; }
  const float4* Xl4 = (const float4*)Xl;
  for (int k0 = 0; k0 < 128; k0 += 4) {
    float2 w0 = *(const float2*)&Wl[(k0 + 0) * 128 + c2];
    float2 w1 = *(const float2*)&Wl[(k0 + 1) * 128 + c2];
    float2 w2 = *(const float2*)&Wl[(k0 + 2) * 128 + c2];
    float2 w3 = *(const float2*)&Wl[(k0 + 3) * 128 + c2];
    #pragma unroll
    for (int j = 0; j < 8; ++j) {
      float4 xv = Xl4[((rg * 8 + j) * 128 + k0) >> 2];
      acc[j][0] = fmaf(xv.x, w0.x, acc[j][0]); acc[j][1] = fmaf(xv.x, w0.y, acc[j][1]);
      acc[j][0] = fmaf(xv.y, w1.x, acc[j][0]); acc[j][1] = fmaf(xv.y, w1.y, acc[j][1]);
      acc[j][0] = fmaf(xv.z, w2.x, acc[j][0]); acc[j][1] = fmaf(xv.z, w2.y, acc[j][1]);
      acc[j][0] = fmaf(xv.w, w3.x, acc[j][0]); acc[j][1] = fmaf(xv.w, w3.y, acc[j][1]);
    }
  }
  #pragma unroll
  for (int j = 0; j < 8; ++j) {
    int lr = rg * 8 + j;
    if (lr < nr) {
      int r = r0 + lr;
      float sc = scale ? scale[r] : 1.0f;
      u32 pk = (u32)f2bf(acc[j][0] * sc) | ((u32)f2bf(acc[j][1] * sc) << 16);
      *(u32*)(OUT + (size_t)r * 128 + c2) = pk;
    }
  }
}

// ---------------- gather-aggregate: one NODE per wave64, halves take even/odd edges ----------
// H[v] = bf16(relu(dinv[v]*(Ts[v] + sum_in Ts[r]) + b)); 4 gathers in flight per wave
__global__ __launch_bounds__(256) void k_gather(const int* __restrict__ ptr, const uint2* __restrict__ sre,
                                                const float* __restrict__ dinv, const u16* __restrict__ Ts,
                                                u16* __restrict__ H, const float* __restrict__ bias) {
  int wid = threadIdx.x >> 6, lane = threadIdx.x & 63;
  int q = lane & 31, eo = lane >> 5;
  int v = blockIdx.x * 4 + wid; if (v >= NND) return;
  int p0 = ptr[v], p1 = ptr[v + 1];
  const uint2* T2 = (const uint2*)Ts;
  float4 acc = make_float4(0.f, 0.f, 0.f, 0.f);
  if (eo == 0) acc = unpack4(T2[(size_t)v * 32 + q]);   // self-loop (Ts pre-scaled by dinv[src])
  for (int j2 = p0; j2 < p1; j2 += 4) {
    int ja = j2 + eo, jb = j2 + 2 + eo;
    bool oka = ja < p1, okb = jb < p1;
    int ra = (int)sre[oka ? ja : p0].x;
    int rb = (int)sre[okb ? jb : p0].x;
    float4 ma = unpack4(T2[(size_t)ra * 32 + q]);
    float4 mb = unpack4(T2[(size_t)rb * 32 + q]);
    if (oka) { acc.x += ma.x; acc.y += ma.y; acc.z += ma.z; acc.w += ma.w; }
    if (okb) { acc.x += mb.x; acc.y += mb.y; acc.z += mb.z; acc.w += mb.w; }
  }
  acc.x += __shfl_xor(acc.x, 32);
  acc.y += __shfl_xor(acc.y, 32);
  acc.z += __shfl_xor(acc.z, 32);
  acc.w += __shfl_xor(acc.w, 32);
  if (eo == 0) {
    float s = dinv[v];
    float4 b = ((const float4*)bias)[q];
    float o0 = fmaxf(fmaf(acc.x, s, b.x), 0.f);
    float o1 = fmaxf(fmaf(acc.y, s, b.y), 0.f);
    float o2 = fmaxf(fmaf(acc.z, s, b.z), 0.f);
    float o3 = fmaxf(fmaf(acc.w, s, b.w), 0.f);
    uint2 o;
    o.x = (u32)f2bf(o0) | ((u32)f2bf(o1) << 16);
    o.y = (u32)f2bf(o2) | ((u32)f2bf(o3) << 16);
    ((uint2*)H)[(size_t)v * 32 + q] = o;
  }
}

// ---------------- edge head: one NODE per wave64, halves take even/odd edges ----------------
__global__ __launch_bounds__(256) void k_edge(const int* __restrict__ ptr, const uint2* __restrict__ sre,
                                              const u16* __restrict__ U, const u16* __restrict__ V,
                                              const float* __restrict__ be1, const float* __restrict__ We2,
                                              const float* __restrict__ be2, float* __restrict__ out) {
  int wid = threadIdx.x >> 6, lane = threadIdx.x & 63;
  int q = lane & 31, eo = lane >> 5;
  int c = blockIdx.x * 4 + wid; if (c >= NND) return;
  int p0 = ptr[c], p1 = ptr[c + 1];
  if (p0 == p1) return;
  const uint2* U2 = (const uint2*)U;
  const uint2* V2 = (const uint2*)V;
  float4 vv = unpack4(V2[(size_t)c * 32 + q]);
  float4 b = ((const float4*)be1)[q];
  vv.x += b.x; vv.y += b.y; vv.z += b.z; vv.w += b.w;
  float4 w2 = ((const float4*)We2)[q];
  float bias2 = be2[0];
  for (int j2 = p0; j2 < p1; j2 += 4) {
    int ja = j2 + eo, jb = j2 + 2 + eo;
    bool oka = ja < p1, okb = jb < p1;
    uint2 ea = sre[oka ? ja : p0];
    uint2 eb = sre[okb ? jb : p0];
    float4 ua = unpack4(U2[(size_t)ea.x * 32 + q]);
    float4 ub = unpack4(U2[(size_t)eb.x * 32 + q]);
    float pa = fmaxf(ua.x + vv.x, 0.f) * w2.x
             + fmaxf(ua.y + vv.y, 0.f) * w2.y
             + fmaxf(ua.z + vv.z, 0.f) * w2.z
             + fmaxf(ua.w + vv.w, 0.f) * w2.w;
    float pb = fmaxf(ub.x + vv.x, 0.f) * w2.x
             + fmaxf(ub.y + vv.y, 0.f) * w2.y
             + fmaxf(ub.z + vv.z, 0.f) * w2.z
             + fmaxf(ub.w + vv.w, 0.f) * w2.w;
    #pragma unroll
    for (int off = 16; off; off >>= 1) {
      pa += __shfl_xor(pa, off);
      pb += __shfl_xor(pb, off);
    }
    if (q == 0 && oka) out[ea.y] = 1.f / (1.f + __expf(-(pa + bias2)));
    if (q == 0 && okb) out[eb.y] = 1.f / (1.f + __expf(-(pb + bias2)));
  }
}

extern "C" void kernel_launch(void* const* d_in, const int* in_sizes, int n_in,
                              void* d_out, int out_size, void* d_ws, size_t ws_size,
                              hipStream_t stream) {
  const float* x   = (const float*)d_in[0];
  const int*   ei  = (const int*)d_in[1];
  const float* W1  = (const float*)d_in[2];
  const float* b1  = (const float*)d_in[3];
  const float* W2  = (const float*)d_in[4];
  const float* b2  = (const float*)d_in[5];
  const float* We1 = (const float*)d_in[6];
  const float* be1 = (const float*)d_in[7];
  const float* We2 = (const float*)d_in[8];
  const float* be2 = (const float*)d_in[9];
  float* out = (float*)d_out;

  const int* row  = ei;
  const int* colp = ei + NE;

  // ws layout (4B units):
  // deg[0,50048) ptr[50048,100352) cursor[100352,150400) dinv[150400,200448)
  // bsum[200448,200704) boff[200704,200960) sre[200960,1800960)
  // xb[1800960,+3.2M) Ts[5000960,+3.2M) H[8200960,+3.2M) U[11400960,+3.2M) V[14600960,+3.2M)
  if (ws_size < (size_t)17800960 * 4) return;
  int*   deg    = (int*)d_ws;
  int*   ptr    = (int*)d_ws + 50048;
  int*   cursor = (int*)d_ws + 100352;
  float* dinv   = (float*)d_ws + 150400;
  int*   bsum   = (int*)d_ws + 200448;
  int*   boff   = (int*)d_ws + 200704;
  uint2* sre    = (uint2*)((int*)d_ws + 200960);
  u16*   xb     = (u16*)((int*)d_ws + 1800960);
  u16*   Ts     = (u16*)((int*)d_ws + 5000960);   // reused as U
  u16*   H      = (u16*)((int*)d_ws + 8200960);
  u16*   U      = (u16*)((int*)d_ws + 11400960);
  u16*   V      = (u16*)((int*)d_ws + 14600960);

  hipMemsetAsync(deg, 0, NND * sizeof(int), stream);
  k_deg  <<<(NE + 255) / 256, 256, 0, stream>>>(colp, deg);
  k_scan1<<<SCAN_B, 256, 0, stream>>>(deg, ptr, bsum);
  k_scan2<<<1, 256, 0, stream>>>(bsum, boff, ptr);
  k_scan3<<<SCAN_B, 256, 0, stream>>>(deg, boff, ptr, cursor, dinv);
  k_place<<<(NE + 255) / 256, 256, 0, stream>>>(row, colp, cursor, sre);
  k_cast <<<(NND * 32 + 255) / 256, 256, 0, stream>>>((const float4*)x, (uint2*)xb);

  int gemm_grid = (NND + 31) / 32;
  int node_grid = (NND + 3) / 4;      // one node per wave64, 4 waves/block

  // layer 1: Ts = bf16((xb@W1)*dinv) ; H = relu(dinv*(Ts_self + gather) + b1)
  k_gemm  <<<gemm_grid, 256, 0, stream>>>(xb, W1, Ts, dinv);
  k_gather<<<node_grid, 256, 0, stream>>>(ptr, sre, dinv, Ts, H, b1);

  // layer 2
  k_gemm  <<<gemm_grid, 256, 0, stream>>>(H, W2, Ts, dinv);
  k_gather<<<node_grid, 256, 0, stream>>>(ptr, sre, dinv, Ts, H, b2);

  // edge head
  k_gemm<<<gemm_grid, 256, 0, stream>>>(H, We1, U, nullptr);
  k_gemm<<<gemm_grid, 256, 0, stream>>>(H, We1 + 128 * 128, V, nullptr);
  k_edge<<<node_grid, 256, 0, stream>>>(ptr, sre, U, V, be1, We2, be2, out);
}

// Round 5
// 388.502 us; speedup vs baseline: 7.9626x; 1.0707x over previous
//
#include <hip/hip_runtime.h>
#include <math.h>

#define NND 50000
#define HD  128
#define NE  800000
#define SCAN_B 196   // ceil(NND/256)

typedef unsigned short u16;
typedef unsigned int   u32;
typedef __attribute__((ext_vector_type(8))) short bf16x8;
typedef __attribute__((ext_vector_type(4))) float f32x4;

__device__ __forceinline__ float bf2f(u32 u) {
  union { u32 i; float f; } v; v.i = u << 16; return v.f;
}
__device__ __forceinline__ u16 f2bf(float f) {
  union { float f; u32 i; } v; v.f = f;
  return (u16)((v.i + 0x7FFFu + ((v.i >> 16) & 1u)) >> 16);
}
__device__ __forceinline__ float4 unpack4(uint2 m) {
  float4 r;
  r.x = bf2f(m.x & 0xFFFFu); r.y = bf2f(m.x >> 16);
  r.z = bf2f(m.y & 0xFFFFu); r.w = bf2f(m.y >> 16);
  return r;
}

// ---------------- degree (in-degree over col) ----------------
__global__ __launch_bounds__(256) void k_deg(const int* __restrict__ col, int* __restrict__ deg) {
  int i = blockIdx.x * 256 + threadIdx.x;
  if (i < NE) atomicAdd(&deg[col[i]], 1);
}

// ---------------- hierarchical scan ----------------
__global__ __launch_bounds__(256) void k_scan1(const int* __restrict__ deg, int* __restrict__ ptr,
                                               int* __restrict__ bsum) {
  __shared__ int ws[4];
  int tid = threadIdx.x, lane = tid & 63, wid = tid >> 6;
  int i = blockIdx.x * 256 + tid;
  int d = (i < NND) ? deg[i] : 0;
  int x = d;
  #pragma unroll
  for (int off = 1; off < 64; off <<= 1) {
    int y = __shfl_up(x, off);
    if (lane >= off) x += y;
  }
  if (lane == 63) ws[wid] = x;
  __syncthreads();
  int woff = 0;
  for (int w = 0; w < wid; ++w) woff += ws[w];
  if (i < NND) ptr[i] = woff + x - d;
  if (tid == 255) bsum[blockIdx.x] = woff + x;
}

__global__ __launch_bounds__(256) void k_scan2(const int* __restrict__ bsum, int* __restrict__ boff,
                                               int* __restrict__ ptr) {
  __shared__ int ws[4];
  int tid = threadIdx.x, lane = tid & 63, wid = tid >> 6;
  int d = (tid < SCAN_B) ? bsum[tid] : 0;
  int x = d;
  #pragma unroll
  for (int off = 1; off < 64; off <<= 1) {
    int y = __shfl_up(x, off);
    if (lane >= off) x += y;
  }
  if (lane == 63) ws[wid] = x;
  __syncthreads();
  int woff = 0;
  for (int w = 0; w < wid; ++w) woff += ws[w];
  if (tid < SCAN_B) boff[tid] = woff + x - d;
  if (tid == 0) ptr[NND] = NE;
}

__global__ __launch_bounds__(256) void k_scan3(const int* __restrict__ deg, const int* __restrict__ boff,
                                               int* __restrict__ ptr, int* __restrict__ cursor,
                                               float* __restrict__ dinv) {
  int i = blockIdx.x * 256 + threadIdx.x;
  if (i >= NND) return;
  int p = ptr[i] + boff[i >> 8];
  ptr[i] = p;
  cursor[i] = p;
  dinv[i] = rsqrtf((float)(deg[i] + 1));
}

// ---------------- counting-sort placement: (row, eid) pairs grouped by col ----------------
__global__ __launch_bounds__(256) void k_place(const int* __restrict__ row, const int* __restrict__ col,
                                               int* __restrict__ cursor, uint2* __restrict__ sre) {
  int e = blockIdx.x * 256 + threadIdx.x;
  if (e >= NE) return;
  int c = col[e];
  int slot = atomicAdd(&cursor[c], 1);
  sre[slot] = make_uint2((u32)row[e], (u32)e);
}

// ---------------- weight prep: transposed bf16 hi/lo splits ----------------
// Wt1[n][k]=W1[k][n]; Wt2 same; Wte[n][k]: n<128 -> We1[k][n], n>=128 -> We1[128+k][n-128]
__global__ __launch_bounds__(256) void k_wprep(const float* __restrict__ W1, const float* __restrict__ W2,
                                               const float* __restrict__ We1,
                                               u16* __restrict__ t1h, u16* __restrict__ t1l,
                                               u16* __restrict__ t2h, u16* __restrict__ t2l,
                                               u16* __restrict__ teh, u16* __restrict__ tel) {
  int idx = blockIdx.x * 256 + threadIdx.x;   // 65536 total
  float w;
  u16 *dh, *dl;
  int j;
  if (idx < 16384) {
    j = idx; int n = j >> 7, k = j & 127;
    w = W1[k * 128 + n]; dh = t1h; dl = t1l;
  } else if (idx < 32768) {
    j = idx - 16384; int n = j >> 7, k = j & 127;
    w = W2[k * 128 + n]; dh = t2h; dl = t2l;
  } else {
    j = idx - 32768; int n = j >> 7, k = j & 127;
    w = (n < 128) ? We1[k * 128 + n] : We1[(128 + k) * 128 + (n - 128)];
    dh = teh; dl = tel;
  }
  u16 hi = f2bf(w);
  float res = w - bf2f((u32)hi);
  dh[j] = hi;
  dl[j] = f2bf(res);
}

// ---------------- MFMA GEMM: OUT[r][n] = bf16( (X[r][:] . Wt[n][:]) * (scale?scale[r]:1) ) -------
// X: [NND][128] (fp32 if AFP32 else bf16). Wt hi/lo: [N][128] bf16. 64 rows/block, 4 waves.
template<int N, bool AFP32>
__global__ __launch_bounds__(256) void k_mm(const void* __restrict__ Xv,
                                            const u16* __restrict__ Whi, const u16* __restrict__ Wlo,
                                            u16* __restrict__ OUT, const float* __restrict__ scale) {
  int wid = threadIdx.x >> 6, lane = threadIdx.x & 63;
  int m16 = lane & 15, kg = lane >> 4;
  int arow = blockIdx.x * 64 + wid * 16 + m16;
  int ar = (arow < NND) ? arow : NND - 1;          // clamp: garbage stays in unstored D rows
  bf16x8 afrag[4];
  if (AFP32) {
    const float* X = (const float*)Xv + (size_t)ar * 128 + kg * 8;
    #pragma unroll
    for (int ks = 0; ks < 4; ++ks) {
      float4 a = *(const float4*)(X + ks * 32);
      float4 b = *(const float4*)(X + ks * 32 + 4);
      union { u32 w[4]; bf16x8 v; } u;
      u.w[0] = (u32)f2bf(a.x) | ((u32)f2bf(a.y) << 16);
      u.w[1] = (u32)f2bf(a.z) | ((u32)f2bf(a.w) << 16);
      u.w[2] = (u32)f2bf(b.x) | ((u32)f2bf(b.y) << 16);
      u.w[3] = (u32)f2bf(b.z) | ((u32)f2bf(b.w) << 16);
      afrag[ks] = u.v;
    }
  } else {
    const u16* X = (const u16*)Xv + (size_t)ar * 128 + kg * 8;
    #pragma unroll
    for (int ks = 0; ks < 4; ++ks) afrag[ks] = *(const bf16x8*)(X + ks * 32);
  }
  int crow0 = blockIdx.x * 64 + wid * 16 + kg * 4;  // C/D: row=(lane>>4)*4+reg, col=lane&15
  float sc[4];
  #pragma unroll
  for (int j = 0; j < 4; ++j)
    sc[j] = (scale != nullptr && crow0 + j < NND) ? scale[crow0 + j] : 1.0f;
  const u16* bh = Whi + (size_t)m16 * 128 + kg * 8;
  const u16* bl = Wlo + (size_t)m16 * 128 + kg * 8;
  #pragma unroll
  for (int t = 0; t < N / 16; ++t) {
    f32x4 acc = {0.f, 0.f, 0.f, 0.f};
    #pragma unroll
    for (int ks = 0; ks < 4; ++ks) {
      bf16x8 bhf = *(const bf16x8*)(bh + (size_t)t * 2048 + ks * 32);
      bf16x8 blf = *(const bf16x8*)(bl + (size_t)t * 2048 + ks * 32);
      acc = __builtin_amdgcn_mfma_f32_16x16x32_bf16(afrag[ks], bhf, acc, 0, 0, 0);
      acc = __builtin_amdgcn_mfma_f32_16x16x32_bf16(afrag[ks], blf, acc, 0, 0, 0);
    }
    #pragma unroll
    for (int j = 0; j < 4; ++j) {
      int r = crow0 + j;
      if (r < NND) OUT[(size_t)r * N + t * 16 + m16] = f2bf(acc[j] * sc[j]);
    }
  }
}

// ---------------- gather-aggregate: one NODE per wave64, halves take even/odd edges ----------
__global__ __launch_bounds__(256) void k_gather(const int* __restrict__ ptr, const uint2* __restrict__ sre,
                                                const float* __restrict__ dinv, const u16* __restrict__ Ts,
                                                u16* __restrict__ H, const float* __restrict__ bias) {
  int wid = threadIdx.x >> 6, lane = threadIdx.x & 63;
  int q = lane & 31, eo = lane >> 5;
  int v = blockIdx.x * 4 + wid; if (v >= NND) return;
  int p0 = ptr[v], p1 = ptr[v + 1];
  const uint2* T2 = (const uint2*)Ts;
  float4 acc = make_float4(0.f, 0.f, 0.f, 0.f);
  if (eo == 0) acc = unpack4(T2[(size_t)v * 32 + q]);   // self-loop (Ts pre-scaled by dinv[src])
  for (int j2 = p0; j2 < p1; j2 += 4) {
    int ja = j2 + eo, jb = j2 + 2 + eo;
    bool oka = ja < p1, okb = jb < p1;
    int ra = (int)sre[oka ? ja : p0].x;
    int rb = (int)sre[okb ? jb : p0].x;
    float4 ma = unpack4(T2[(size_t)ra * 32 + q]);
    float4 mb = unpack4(T2[(size_t)rb * 32 + q]);
    if (oka) { acc.x += ma.x; acc.y += ma.y; acc.z += ma.z; acc.w += ma.w; }
    if (okb) { acc.x += mb.x; acc.y += mb.y; acc.z += mb.z; acc.w += mb.w; }
  }
  acc.x += __shfl_xor(acc.x, 32);
  acc.y += __shfl_xor(acc.y, 32);
  acc.z += __shfl_xor(acc.z, 32);
  acc.w += __shfl_xor(acc.w, 32);
  if (eo == 0) {
    float s = dinv[v];
    float4 b = ((const float4*)bias)[q];
    float o0 = fmaxf(fmaf(acc.x, s, b.x), 0.f);
    float o1 = fmaxf(fmaf(acc.y, s, b.y), 0.f);
    float o2 = fmaxf(fmaf(acc.z, s, b.z), 0.f);
    float o3 = fmaxf(fmaf(acc.w, s, b.w), 0.f);
    uint2 o;
    o.x = (u32)f2bf(o0) | ((u32)f2bf(o1) << 16);
    o.y = (u32)f2bf(o2) | ((u32)f2bf(o3) << 16);
    ((uint2*)H)[(size_t)v * 32 + q] = o;
  }
}

// ---------------- edge head: one NODE per wave64, halves take even/odd edges ----------------
// UV: [NND][256] bf16 (U = cols 0..127, V = cols 128..255)
__global__ __launch_bounds__(256) void k_edge(const int* __restrict__ ptr, const uint2* __restrict__ sre,
                                              const u16* __restrict__ UV,
                                              const float* __restrict__ be1, const float* __restrict__ We2,
                                              const float* __restrict__ be2, float* __restrict__ out) {
  int wid = threadIdx.x >> 6, lane = threadIdx.x & 63;
  int q = lane & 31, eo = lane >> 5;
  int c = blockIdx.x * 4 + wid; if (c >= NND) return;
  int p0 = ptr[c], p1 = ptr[c + 1];
  if (p0 == p1) return;
  const uint2* UV2 = (const uint2*)UV;
  float4 vv = unpack4(UV2[(size_t)c * 64 + 32 + q]);
  float4 b = ((const float4*)be1)[q];
  vv.x += b.x; vv.y += b.y; vv.z += b.z; vv.w += b.w;
  float4 w2 = ((const float4*)We2)[q];
  float bias2 = be2[0];
  for (int j2 = p0; j2 < p1; j2 += 4) {
    int ja = j2 + eo, jb = j2 + 2 + eo;
    bool oka = ja < p1, okb = jb < p1;
    uint2 ea = sre[oka ? ja : p0];
    uint2 eb = sre[okb ? jb : p0];
    float4 ua = unpack4(UV2[(size_t)ea.x * 64 + q]);
    float4 ub = unpack4(UV2[(size_t)eb.x * 64 + q]);
    float pa = fmaxf(ua.x + vv.x, 0.f) * w2.x
             + fmaxf(ua.y + vv.y, 0.f) * w2.y
             + fmaxf(ua.z + vv.z, 0.f) * w2.z
             + fmaxf(ua.w + vv.w, 0.f) * w2.w;
    float pb = fmaxf(ub.x + vv.x, 0.f) * w2.x
             + fmaxf(ub.y + vv.y, 0.f) * w2.y
             + fmaxf(ub.z + vv.z, 0.f) * w2.z
             + fmaxf(ub.w + vv.w, 0.f) * w2.w;
    #pragma unroll
    for (int off = 16; off; off >>= 1) {
      pa += __shfl_xor(pa, off);
      pb += __shfl_xor(pb, off);
    }
    if (q == 0 && oka) out[ea.y] = 1.f / (1.f + __expf(-(pa + bias2)));
    if (q == 0 && okb) out[eb.y] = 1.f / (1.f + __expf(-(pb + bias2)));
  }
}

extern "C" void kernel_launch(void* const* d_in, const int* in_sizes, int n_in,
                              void* d_out, int out_size, void* d_ws, size_t ws_size,
                              hipStream_t stream) {
  const float* x   = (const float*)d_in[0];
  const int*   ei  = (const int*)d_in[1];
  const float* W1  = (const float*)d_in[2];
  const float* b1  = (const float*)d_in[3];
  const float* W2  = (const float*)d_in[4];
  const float* b2  = (const float*)d_in[5];
  const float* We1 = (const float*)d_in[6];
  const float* be1 = (const float*)d_in[7];
  const float* We2 = (const float*)d_in[8];
  const float* be2 = (const float*)d_in[9];
  float* out = (float*)d_out;

  const int* row  = ei;
  const int* colp = ei + NE;

  // ws layout (u32 units):
  // deg[0,50048) ptr[50048,100352) cursor[100352,150400) dinv[150400,200448)
  // bsum[200448,200704) boff[200704,200960) sre[200960,1800960)
  // Wt1h[1800960,+8192) Wt1l[1809152) Wt2h[1817344) Wt2l[1825536) Wteh[1833728,+16384) Wtel[1850112,+16384)
  // Ts[1866496,+3.2M) H[5066496,+3.2M) UV[8266496,+6.4M)  end 14666496
  if (ws_size < (size_t)14666496 * 4) return;
  int*   deg    = (int*)d_ws;
  int*   ptr    = (int*)d_ws + 50048;
  int*   cursor = (int*)d_ws + 100352;
  float* dinv   = (float*)d_ws + 150400;
  int*   bsum   = (int*)d_ws + 200448;
  int*   boff   = (int*)d_ws + 200704;
  uint2* sre    = (uint2*)((int*)d_ws + 200960);
  u16*   t1h    = (u16*)((int*)d_ws + 1800960);
  u16*   t1l    = (u16*)((int*)d_ws + 1809152);
  u16*   t2h    = (u16*)((int*)d_ws + 1817344);
  u16*   t2l    = (u16*)((int*)d_ws + 1825536);
  u16*   teh    = (u16*)((int*)d_ws + 1833728);
  u16*   tel    = (u16*)((int*)d_ws + 1850112);
  u16*   Ts     = (u16*)((int*)d_ws + 1866496);
  u16*   H      = (u16*)((int*)d_ws + 5066496);
  u16*   UV     = (u16*)((int*)d_ws + 8266496);

  hipMemsetAsync(deg, 0, NND * sizeof(int), stream);
  k_wprep<<<256, 256, 0, stream>>>(W1, W2, We1, t1h, t1l, t2h, t2l, teh, tel);
  k_deg  <<<(NE + 255) / 256, 256, 0, stream>>>(colp, deg);
  k_scan1<<<SCAN_B, 256, 0, stream>>>(deg, ptr, bsum);
  k_scan2<<<1, 256, 0, stream>>>(bsum, boff, ptr);
  k_scan3<<<SCAN_B, 256, 0, stream>>>(deg, boff, ptr, cursor, dinv);
  k_place<<<(NE + 255) / 256, 256, 0, stream>>>(row, colp, cursor, sre);

  int mm_grid   = (NND + 63) / 64;
  int node_grid = (NND + 3) / 4;      // one node per wave64, 4 waves/block

  // layer 1: Ts = bf16((x@W1)*dinv) ; H = relu(dinv*(Ts_self + gather) + b1)
  k_mm<128, true><<<mm_grid, 256, 0, stream>>>(x, t1h, t1l, Ts, dinv);
  k_gather<<<node_grid, 256, 0, stream>>>(ptr, sre, dinv, Ts, H, b1);

  // layer 2
  k_mm<128, false><<<mm_grid, 256, 0, stream>>>(H, t2h, t2l, Ts, dinv);
  k_gather<<<node_grid, 256, 0, stream>>>(ptr, sre, dinv, Ts, H, b2);

  // edge head: UV = H @ [We1_top | We1_bot]  (one fused N=256 GEMM), then per-edge
  k_mm<256, false><<<mm_grid, 256, 0, stream>>>(H, teh, tel, UV, nullptr);
  k_edge<<<node_grid, 256, 0, stream>>>(ptr, sre, UV, be1, We2, be2, out);
}

// Round 6
// 277.230 us; speedup vs baseline: 11.1586x; 1.4014x over previous
//
#include <hip/hip_runtime.h>
#include <math.h>

#define NND 50000
#define HD  128
#define NE  800000
#define SCAN_B 196   // ceil(NND/256)

typedef unsigned short u16;
typedef unsigned int   u32;
typedef __attribute__((ext_vector_type(8))) short bf16x8;
typedef __attribute__((ext_vector_type(4))) float f32x4;

__device__ __forceinline__ float bf2f(u32 u) {
  union { u32 i; float f; } v; v.i = u << 16; return v.f;
}
__device__ __forceinline__ u16 f2bf(float f) {
  union { float f; u32 i; } v; v.f = f;
  return (u16)((v.i + 0x7FFFu + ((v.i >> 16) & 1u)) >> 16);
}
__device__ __forceinline__ float4 unpack4(uint2 m) {
  float4 r;
  r.x = bf2f(m.x & 0xFFFFu); r.y = bf2f(m.x >> 16);
  r.z = bf2f(m.y & 0xFFFFu); r.w = bf2f(m.y >> 16);
  return r;
}

// ---------------- degree (in-degree over col) ----------------
__global__ __launch_bounds__(256) void k_deg(const int* __restrict__ col, int* __restrict__ deg) {
  int i = blockIdx.x * 256 + threadIdx.x;
  if (i < NE) atomicAdd(&deg[col[i]], 1);
}

// ---------------- hierarchical scan ----------------
__global__ __launch_bounds__(256) void k_scan1(const int* __restrict__ deg, int* __restrict__ ptr,
                                               int* __restrict__ bsum) {
  __shared__ int ws[4];
  int tid = threadIdx.x, lane = tid & 63, wid = tid >> 6;
  int i = blockIdx.x * 256 + tid;
  int d = (i < NND) ? deg[i] : 0;
  int x = d;
  #pragma unroll
  for (int off = 1; off < 64; off <<= 1) {
    int y = __shfl_up(x, off);
    if (lane >= off) x += y;
  }
  if (lane == 63) ws[wid] = x;
  __syncthreads();
  int woff = 0;
  for (int w = 0; w < wid; ++w) woff += ws[w];
  if (i < NND) ptr[i] = woff + x - d;
  if (tid == 255) bsum[blockIdx.x] = woff + x;
}

__global__ __launch_bounds__(256) void k_scan2(const int* __restrict__ bsum, int* __restrict__ boff,
                                               int* __restrict__ ptr) {
  __shared__ int ws[4];
  int tid = threadIdx.x, lane = tid & 63, wid = tid >> 6;
  int d = (tid < SCAN_B) ? bsum[tid] : 0;
  int x = d;
  #pragma unroll
  for (int off = 1; off < 64; off <<= 1) {
    int y = __shfl_up(x, off);
    if (lane >= off) x += y;
  }
  if (lane == 63) ws[wid] = x;
  __syncthreads();
  int woff = 0;
  for (int w = 0; w < wid; ++w) woff += ws[w];
  if (tid < SCAN_B) boff[tid] = woff + x - d;
  if (tid == 0) ptr[NND] = NE;
}

__global__ __launch_bounds__(256) void k_scan3(const int* __restrict__ deg, const int* __restrict__ boff,
                                               int* __restrict__ ptr, int* __restrict__ cursor,
                                               float* __restrict__ dinv) {
  int i = blockIdx.x * 256 + threadIdx.x;
  if (i >= NND) return;
  int p = ptr[i] + boff[i >> 8];
  ptr[i] = p;
  cursor[i] = p;
  dinv[i] = rsqrtf((float)(deg[i] + 1));
}

// ---------------- counting-sort placement: (row, eid) pairs grouped by col ----------------
__global__ __launch_bounds__(256) void k_place(const int* __restrict__ row, const int* __restrict__ col,
                                               int* __restrict__ cursor, uint2* __restrict__ sre) {
  int e = blockIdx.x * 256 + threadIdx.x;
  if (e >= NE) return;
  int c = col[e];
  int slot = atomicAdd(&cursor[c], 1);
  sre[slot] = make_uint2((u32)row[e], (u32)e);
}

// ---------------- weight prep: transposed bf16 hi/lo, LDS-swizzled layout ----------------
// element (n,k) stored at u16-index n*128 + ((k>>3 ^ (n&7))<<3) + (k&7)
// so a blind linear copy into LDS gives bank-conflict-free swizzled reads.
__global__ __launch_bounds__(256) void k_wprep(const float* __restrict__ W1, const float* __restrict__ W2,
                                               const float* __restrict__ We1,
                                               u16* __restrict__ t1h, u16* __restrict__ t1l,
                                               u16* __restrict__ t2h, u16* __restrict__ t2l,
                                               u16* __restrict__ teh, u16* __restrict__ tel) {
  int idx = blockIdx.x * 256 + threadIdx.x;   // 65536 total
  float w;
  u16 *dh, *dl;
  int j;
  if (idx < 16384) {
    j = idx; int n = j >> 7, k = j & 127;
    w = W1[k * 128 + n]; dh = t1h; dl = t1l;
  } else if (idx < 32768) {
    j = idx - 16384; int n = j >> 7, k = j & 127;
    w = W2[k * 128 + n]; dh = t2h; dl = t2l;
  } else {
    j = idx - 32768; int n = j >> 7, k = j & 127;
    w = (n < 128) ? We1[k * 128 + n] : We1[(128 + k) * 128 + (n - 128)];
    dh = teh; dl = tel;
  }
  int n = j >> 7, k = j & 127;
  int sidx = n * 128 + ((((k >> 3) ^ (n & 7))) << 3) + (k & 7);
  u16 hi = f2bf(w);
  float res = w - bf2f((u32)hi);
  dh[sidx] = hi;
  dl[sidx] = f2bf(res);
}

// ---------------- MFMA GEMM, LDS-staged B ----------------
// OUT[r][n] = bf16( (X[r][:] . Wt[n][:]) * (scale?scale[r]:1) )
// X: [NND][128] (fp32 if AFP32 else bf16). Wt hi/lo: swizzled [N][128] bf16.
// 64 rows/block, 4 waves; B staged per 128-col chunk (64 KB LDS).
template<int N, bool AFP32>
__global__ __launch_bounds__(256) void k_mm(const void* __restrict__ Xv,
                                            const u16* __restrict__ Whi, const u16* __restrict__ Wlo,
                                            u16* __restrict__ OUT, const float* __restrict__ scale) {
  __shared__ __align__(16) u16 Bh[128 * 128];   // 32 KB
  __shared__ __align__(16) u16 Bl[128 * 128];   // 32 KB
  int tid = threadIdx.x;
  int wid = tid >> 6, lane = tid & 63;
  int m16 = lane & 15, kg = lane >> 4;
  int arow = blockIdx.x * 64 + wid * 16 + m16;
  int ar = (arow < NND) ? arow : NND - 1;          // clamp: garbage stays in unstored D rows
  bf16x8 afrag[4];
  if (AFP32) {
    const float* X = (const float*)Xv + (size_t)ar * 128 + kg * 8;
    #pragma unroll
    for (int ks = 0; ks < 4; ++ks) {
      float4 a = *(const float4*)(X + ks * 32);
      float4 b = *(const float4*)(X + ks * 32 + 4);
      union { u32 w[4]; bf16x8 v; } u;
      u.w[0] = (u32)f2bf(a.x) | ((u32)f2bf(a.y) << 16);
      u.w[1] = (u32)f2bf(a.z) | ((u32)f2bf(a.w) << 16);
      u.w[2] = (u32)f2bf(b.x) | ((u32)f2bf(b.y) << 16);
      u.w[3] = (u32)f2bf(b.z) | ((u32)f2bf(b.w) << 16);
      afrag[ks] = u.v;
    }
  } else {
    const u16* X = (const u16*)Xv + (size_t)ar * 128 + kg * 8;
    #pragma unroll
    for (int ks = 0; ks < 4; ++ks) afrag[ks] = *(const bf16x8*)(X + ks * 32);
  }
  int crow0 = blockIdx.x * 64 + wid * 16 + kg * 4;  // C/D: row=(lane>>4)*4+reg, col=lane&15
  float sc[4];
  #pragma unroll
  for (int j = 0; j < 4; ++j)
    sc[j] = (scale != nullptr && crow0 + j < NND) ? scale[crow0 + j] : 1.0f;

  #pragma unroll
  for (int ch = 0; ch < N / 128; ++ch) {
    if (ch) __syncthreads();                      // all waves done with previous chunk
    // stage 64 KB: linear copy (layout pre-swizzled by k_wprep)
    const uint4* gh = (const uint4*)(Whi + (size_t)ch * 128 * 128);
    const uint4* gl = (const uint4*)(Wlo + (size_t)ch * 128 * 128);
    uint4* lh = (uint4*)Bh;
    uint4* ll = (uint4*)Bl;
    #pragma unroll
    for (int i = 0; i < 8; ++i) {
      lh[tid + i * 256] = gh[tid + i * 256];
      ll[tid + i * 256] = gl[tid + i * 256];
    }
    __syncthreads();
    #pragma unroll
    for (int t = 0; t < 8; ++t) {
      int col = t * 16 + m16;
      f32x4 acc = {0.f, 0.f, 0.f, 0.f};
      #pragma unroll
      for (int ks = 0; ks < 4; ++ks) {
        int c8 = (ks * 4 + kg) ^ (col & 7);
        bf16x8 bhf = *(const bf16x8*)(Bh + col * 128 + c8 * 8);
        bf16x8 blf = *(const bf16x8*)(Bl + col * 128 + c8 * 8);
        acc = __builtin_amdgcn_mfma_f32_16x16x32_bf16(afrag[ks], bhf, acc, 0, 0, 0);
        acc = __builtin_amdgcn_mfma_f32_16x16x32_bf16(afrag[ks], blf, acc, 0, 0, 0);
      }
      #pragma unroll
      for (int j = 0; j < 4; ++j) {
        int r = crow0 + j;
        if (r < NND) OUT[(size_t)r * N + ch * 128 + t * 16 + m16] = f2bf(acc[j] * sc[j]);
      }
    }
  }
}

// ---------------- gather-aggregate: one NODE per wave64, 8 gathers in flight ----------
__global__ __launch_bounds__(256) void k_gather(const int* __restrict__ ptr, const uint2* __restrict__ sre,
                                                const float* __restrict__ dinv, const u16* __restrict__ Ts,
                                                u16* __restrict__ H, const float* __restrict__ bias) {
  int wid = threadIdx.x >> 6, lane = threadIdx.x & 63;
  int q = lane & 31, eo = lane >> 5;
  int v = blockIdx.x * 4 + wid; if (v >= NND) return;
  int p0 = ptr[v], p1 = ptr[v + 1];
  const uint2* T2 = (const uint2*)Ts;
  float4 acc = make_float4(0.f, 0.f, 0.f, 0.f);
  if (eo == 0) acc = unpack4(T2[(size_t)v * 32 + q]);   // self-loop (Ts pre-scaled by dinv[src])
  for (int j2 = p0; j2 < p1; j2 += 8) {
    bool ok[4]; int r[4];
    #pragma unroll
    for (int s = 0; s < 4; ++s) {
      int j = j2 + s * 2 + eo;
      ok[s] = j < p1;
      r[s] = (int)sre[ok[s] ? j : p0].x;
    }
    float4 m[4];
    #pragma unroll
    for (int s = 0; s < 4; ++s) m[s] = unpack4(T2[(size_t)r[s] * 32 + q]);
    #pragma unroll
    for (int s = 0; s < 4; ++s)
      if (ok[s]) { acc.x += m[s].x; acc.y += m[s].y; acc.z += m[s].z; acc.w += m[s].w; }
  }
  acc.x += __shfl_xor(acc.x, 32);
  acc.y += __shfl_xor(acc.y, 32);
  acc.z += __shfl_xor(acc.z, 32);
  acc.w += __shfl_xor(acc.w, 32);
  if (eo == 0) {
    float s = dinv[v];
    float4 b = ((const float4*)bias)[q];
    float o0 = fmaxf(fmaf(acc.x, s, b.x), 0.f);
    float o1 = fmaxf(fmaf(acc.y, s, b.y), 0.f);
    float o2 = fmaxf(fmaf(acc.z, s, b.z), 0.f);
    float o3 = fmaxf(fmaf(acc.w, s, b.w), 0.f);
    uint2 o;
    o.x = (u32)f2bf(o0) | ((u32)f2bf(o1) << 16);
    o.y = (u32)f2bf(o2) | ((u32)f2bf(o3) << 16);
    ((uint2*)H)[(size_t)v * 32 + q] = o;
  }
}

// ---------------- edge head: one NODE per wave64, 8 gathers in flight ----------------
// UV: [NND][256] bf16 (U = cols 0..127, V = cols 128..255)
__global__ __launch_bounds__(256) void k_edge(const int* __restrict__ ptr, const uint2* __restrict__ sre,
                                              const u16* __restrict__ UV,
                                              const float* __restrict__ be1, const float* __restrict__ We2,
                                              const float* __restrict__ be2, float* __restrict__ out) {
  int wid = threadIdx.x >> 6, lane = threadIdx.x & 63;
  int q = lane & 31, eo = lane >> 5;
  int c = blockIdx.x * 4 + wid; if (c >= NND) return;
  int p0 = ptr[c], p1 = ptr[c + 1];
  if (p0 == p1) return;
  const uint2* UV2 = (const uint2*)UV;
  float4 vv = unpack4(UV2[(size_t)c * 64 + 32 + q]);
  float4 b = ((const float4*)be1)[q];
  vv.x += b.x; vv.y += b.y; vv.z += b.z; vv.w += b.w;
  float4 w2 = ((const float4*)We2)[q];
  float bias2 = be2[0];
  for (int j2 = p0; j2 < p1; j2 += 8) {
    bool ok[4]; uint2 e[4];
    #pragma unroll
    for (int s = 0; s < 4; ++s) {
      int j = j2 + s * 2 + eo;
      ok[s] = j < p1;
      e[s] = sre[ok[s] ? j : p0];
    }
    float4 u[4];
    #pragma unroll
    for (int s = 0; s < 4; ++s) u[s] = unpack4(UV2[(size_t)e[s].x * 64 + q]);
    float p[4];
    #pragma unroll
    for (int s = 0; s < 4; ++s) {
      p[s] = fmaxf(u[s].x + vv.x, 0.f) * w2.x
           + fmaxf(u[s].y + vv.y, 0.f) * w2.y
           + fmaxf(u[s].z + vv.z, 0.f) * w2.z
           + fmaxf(u[s].w + vv.w, 0.f) * w2.w;
    }
    #pragma unroll
    for (int off = 16; off; off >>= 1) {
      p[0] += __shfl_xor(p[0], off);
      p[1] += __shfl_xor(p[1], off);
      p[2] += __shfl_xor(p[2], off);
      p[3] += __shfl_xor(p[3], off);
    }
    if (q == 0) {
      #pragma unroll
      for (int s = 0; s < 4; ++s)
        if (ok[s]) out[e[s].y] = 1.f / (1.f + __expf(-(p[s] + bias2)));
    }
  }
}

extern "C" void kernel_launch(void* const* d_in, const int* in_sizes, int n_in,
                              void* d_out, int out_size, void* d_ws, size_t ws_size,
                              hipStream_t stream) {
  const float* x   = (const float*)d_in[0];
  const int*   ei  = (const int*)d_in[1];
  const float* W1  = (const float*)d_in[2];
  const float* b1  = (const float*)d_in[3];
  const float* W2  = (const float*)d_in[4];
  const float* b2  = (const float*)d_in[5];
  const float* We1 = (const float*)d_in[6];
  const float* be1 = (const float*)d_in[7];
  const float* We2 = (const float*)d_in[8];
  const float* be2 = (const float*)d_in[9];
  float* out = (float*)d_out;

  const int* row  = ei;
  const int* colp = ei + NE;

  // ws layout (u32 units):
  // deg[0,50048) ptr[50048,100352) cursor[100352,150400) dinv[150400,200448)
  // bsum[200448,200704) boff[200704,200960) sre[200960,1800960)
  // Wt1h[1800960,+8192) Wt1l[1809152) Wt2h[1817344) Wt2l[1825536) Wteh[1833728,+16384) Wtel[1850112,+16384)
  // Ts[1866496,+3.2M) H[5066496,+3.2M) UV[8266496,+6.4M)  end 14666496
  if (ws_size < (size_t)14666496 * 4) return;
  int*   deg    = (int*)d_ws;
  int*   ptr    = (int*)d_ws + 50048;
  int*   cursor = (int*)d_ws + 100352;
  float* dinv   = (float*)d_ws + 150400;
  int*   bsum   = (int*)d_ws + 200448;
  int*   boff   = (int*)d_ws + 200704;
  uint2* sre    = (uint2*)((int*)d_ws + 200960);
  u16*   t1h    = (u16*)((int*)d_ws + 1800960);
  u16*   t1l    = (u16*)((int*)d_ws + 1809152);
  u16*   t2h    = (u16*)((int*)d_ws + 1817344);
  u16*   t2l    = (u16*)((int*)d_ws + 1825536);
  u16*   teh    = (u16*)((int*)d_ws + 1833728);
  u16*   tel    = (u16*)((int*)d_ws + 1850112);
  u16*   Ts     = (u16*)((int*)d_ws + 1866496);
  u16*   H      = (u16*)((int*)d_ws + 5066496);
  u16*   UV     = (u16*)((int*)d_ws + 8266496);

  hipMemsetAsync(deg, 0, NND * sizeof(int), stream);
  k_wprep<<<256, 256, 0, stream>>>(W1, W2, We1, t1h, t1l, t2h, t2l, teh, tel);
  k_deg  <<<(NE + 255) / 256, 256, 0, stream>>>(colp, deg);
  k_scan1<<<SCAN_B, 256, 0, stream>>>(deg, ptr, bsum);
  k_scan2<<<1, 256, 0, stream>>>(bsum, boff, ptr);
  k_scan3<<<SCAN_B, 256, 0, stream>>>(deg, boff, ptr, cursor, dinv);
  k_place<<<(NE + 255) / 256, 256, 0, stream>>>(row, colp, cursor, sre);

  int mm_grid   = (NND + 63) / 64;
  int node_grid = (NND + 3) / 4;      // one node per wave64, 4 waves/block

  // layer 1: Ts = bf16((x@W1)*dinv) ; H = relu(dinv*(Ts_self + gather) + b1)
  k_mm<128, true><<<mm_grid, 256, 0, stream>>>(x, t1h, t1l, Ts, dinv);
  k_gather<<<node_grid, 256, 0, stream>>>(ptr, sre, dinv, Ts, H, b1);

  // layer 2
  k_mm<128, false><<<mm_grid, 256, 0, stream>>>(H, t2h, t2l, Ts, dinv);
  k_gather<<<node_grid, 256, 0, stream>>>(ptr, sre, dinv, Ts, H, b2);

  // edge head: UV = H @ [We1_top | We1_bot]  (one fused N=256 GEMM), then per-edge
  k_mm<256, false><<<mm_grid, 256, 0, stream>>>(H, teh, tel, UV, nullptr);
  k_edge<<<node_grid, 256, 0, stream>>>(ptr, sre, UV, be1, We2, be2, out);
}

// Round 7
// 244.462 us; speedup vs baseline: 12.6543x; 1.1340x over previous
//
#include <hip/hip_runtime.h>
#include <math.h>

#define NND 50000
#define HD  128
#define NE  800000
#define NBK 196          // buckets of 256 nodes: col>>8, max 195
#define BINB 391         // ceil(NE/2048)
#define NCH 391          // ceil(50048/128) row chunks for k_mm

typedef unsigned short u16;
typedef unsigned int   u32;
typedef __attribute__((ext_vector_type(8))) short bf16x8;
typedef __attribute__((ext_vector_type(4))) float f32x4;

__device__ __forceinline__ float bf2f(u32 u) {
  union { u32 i; float f; } v; v.i = u << 16; return v.f;
}
__device__ __forceinline__ u16 f2bf(float f) {
  union { float f; u32 i; } v; v.f = f;
  return (u16)((v.i + 0x7FFFu + ((v.i >> 16) & 1u)) >> 16);
}
__device__ __forceinline__ float4 unpack4(uint2 m) {
  float4 r;
  r.x = bf2f(m.x & 0xFFFFu); r.y = bf2f(m.x >> 16);
  r.z = bf2f(m.y & 0xFFFFu); r.w = bf2f(m.y >> 16);
  return r;
}

// ---------------- bucket histogram: bhist[b] = #edges with col>>8 == b ----------------
__global__ __launch_bounds__(256) void k_hist(const int* __restrict__ col, u32* __restrict__ bhist) {
  __shared__ u32 lh[NBK];
  int tid = threadIdx.x;
  if (tid < NBK) lh[tid] = 0;
  __syncthreads();
  int e0 = blockIdx.x * 2048;
  #pragma unroll
  for (int s = 0; s < 8; ++s) {
    int e = e0 + s * 256 + tid;
    if (e < NE) atomicAdd(&lh[col[e] >> 8], 1u);
  }
  __syncthreads();
  if (tid < NBK && lh[tid]) atomicAdd(&bhist[tid], lh[tid]);
}

// ---------------- scan bucket counts -> bbase, bcur ----------------
__global__ __launch_bounds__(256) void k_bscan(const u32* __restrict__ bhist, u32* __restrict__ bbase,
                                               u32* __restrict__ bcur) {
  __shared__ u32 ws[4];
  int tid = threadIdx.x, lane = tid & 63, wid = tid >> 6;
  u32 d = (tid < NBK) ? bhist[tid] : 0;
  u32 x = d;
  #pragma unroll
  for (int off = 1; off < 64; off <<= 1) {
    u32 y = __shfl_up(x, off);
    if (lane >= off) x += y;
  }
  if (lane == 63) ws[wid] = x;
  __syncthreads();
  u32 woff = 0;
  for (int w = 0; w < wid; ++w) woff += ws[w];
  if (tid < NBK) { bbase[tid] = woff + x - d; bcur[tid] = woff + x - d; }
}

// ---------------- binning: block-aggregated contiguous reservations per bucket --------
// record: x = row | ((col&255)<<16), y = eid
__global__ __launch_bounds__(256) void k_bin(const int* __restrict__ row, const int* __restrict__ col,
                                             u32* __restrict__ bcur, uint2* __restrict__ recs) {
  __shared__ u32 lcount[NBK], lbase[NBK];
  int tid = threadIdx.x;
  if (tid < NBK) lcount[tid] = 0;
  __syncthreads();
  int e0 = blockIdx.x * 2048;
  u32 rank[8]; int cv[8];
  #pragma unroll
  for (int s = 0; s < 8; ++s) {
    int e = e0 + s * 256 + tid;
    if (e < NE) {
      cv[s] = col[e];
      rank[s] = atomicAdd(&lcount[cv[s] >> 8], 1u);
    }
  }
  __syncthreads();
  if (tid < NBK && lcount[tid]) lbase[tid] = atomicAdd(&bcur[tid], lcount[tid]);
  __syncthreads();
  #pragma unroll
  for (int s = 0; s < 8; ++s) {
    int e = e0 + s * 256 + tid;
    if (e < NE) {
      int c = cv[s];
      u32 slot = lbase[c >> 8] + rank[s];
      recs[slot] = make_uint2((u32)row[e] | (((u32)c & 255u) << 16), (u32)e);
    }
  }
}

// ---------------- fine sort within bucket; emits sre, ptr, dinv ----------------
__global__ __launch_bounds__(256) void k_fine(const u32* __restrict__ bhist, const u32* __restrict__ bbase,
                                              const uint2* __restrict__ recs, uint2* __restrict__ sre,
                                              int* __restrict__ ptr, float* __restrict__ dinv) {
  __shared__ u32 lh[256];
  __shared__ u32 ws[4];
  int b = blockIdx.x, tid = threadIdx.x, lane = tid & 63, wid = tid >> 6;
  u32 base = bbase[b], cnt = bhist[b];
  lh[tid] = 0;
  __syncthreads();
  for (u32 i = tid; i < cnt; i += 256) atomicAdd(&lh[(recs[base + i].x >> 16) & 255u], 1u);
  __syncthreads();
  u32 ci = lh[tid];
  u32 x = ci;
  #pragma unroll
  for (int off = 1; off < 64; off <<= 1) {
    u32 y = __shfl_up(x, off);
    if (lane >= off) x += y;
  }
  if (lane == 63) ws[wid] = x;
  __syncthreads();
  u32 woff = 0;
  for (int w = 0; w < wid; ++w) woff += ws[w];
  u32 excl = woff + x - ci;
  int node = b * 256 + tid;
  if (node <= NND) ptr[node] = (int)(base + excl);
  if (node < NND) dinv[node] = rsqrtf((float)(ci + 1));
  __syncthreads();
  lh[tid] = excl;                 // cursors
  __syncthreads();
  for (u32 i = tid; i < cnt; i += 256) {
    uint2 rec = recs[base + i];
    u32 r = atomicAdd(&lh[(rec.x >> 16) & 255u], 1u);
    sre[base + r] = make_uint2(rec.x & 0xFFFFu, rec.y);
  }
}

// ---------------- weight prep: transposed bf16 hi/lo, LDS-swizzled layout ----------------
// element (n,k) stored at u16-index n*128 + ((k>>3 ^ (n&7))<<3) + (k&7)
__global__ __launch_bounds__(256) void k_wprep(const float* __restrict__ W1, const float* __restrict__ W2,
                                               const float* __restrict__ We1,
                                               u16* __restrict__ t1h, u16* __restrict__ t1l,
                                               u16* __restrict__ t2h, u16* __restrict__ t2l,
                                               u16* __restrict__ teh, u16* __restrict__ tel) {
  int idx = blockIdx.x * 256 + threadIdx.x;   // 65536 total
  float w;
  u16 *dh, *dl;
  int j;
  if (idx < 16384) {
    j = idx; int n = j >> 7, k = j & 127;
    w = W1[k * 128 + n]; dh = t1h; dl = t1l;
  } else if (idx < 32768) {
    j = idx - 16384; int n = j >> 7, k = j & 127;
    w = W2[k * 128 + n]; dh = t2h; dl = t2l;
  } else {
    j = idx - 32768; int n = j >> 7, k = j & 127;
    w = (n < 128) ? We1[k * 128 + n] : We1[(128 + k) * 128 + (n - 128)];
    dh = teh; dl = tel;
  }
  int n = j >> 7, k = j & 127;
  int sidx = n * 128 + ((((k >> 3) ^ (n & 7))) << 3) + (k & 7);
  u16 hi = f2bf(w);
  float res = w - bf2f((u32)hi);
  dh[sidx] = hi;
  dl[sidx] = f2bf(res);
}

// ---------------- persistent-W MFMA GEMM ----------------
// OUT[r][ooff+n] = bf16( (X[r][:] . Wt[n][:]) * (scale?scale[r]:1) ), n in [0,128)
// 512 threads / 8 waves; stage W hi/lo (64 KB) once; loop 128-row chunks, no loop barriers.
template<bool AFP32>
__global__ __launch_bounds__(512) void k_mm(const void* __restrict__ Xv,
                                            const u16* __restrict__ Whi, const u16* __restrict__ Wlo,
                                            u16* __restrict__ OUT, const float* __restrict__ scale,
                                            int ostride, int ooff) {
  __shared__ __align__(16) u16 Bh[128 * 128];   // 32 KB
  __shared__ __align__(16) u16 Bl[128 * 128];   // 32 KB
  int tid = threadIdx.x;
  {
    const uint4* gh = (const uint4*)Whi;
    const uint4* gl = (const uint4*)Wlo;
    uint4* lh = (uint4*)Bh;
    uint4* ll = (uint4*)Bl;
    #pragma unroll
    for (int i = 0; i < 4; ++i) {
      lh[tid + i * 512] = gh[tid + i * 512];
      ll[tid + i * 512] = gl[tid + i * 512];
    }
  }
  __syncthreads();
  int wid = tid >> 6, lane = tid & 63;
  int m16 = lane & 15, kg = lane >> 4;
  for (int chunk = blockIdx.x; chunk < NCH; chunk += gridDim.x) {
    int arow = chunk * 128 + wid * 16 + m16;
    int ar = (arow < NND) ? arow : NND - 1;        // clamp: garbage stays in unstored D rows
    bf16x8 afrag[4];
    if (AFP32) {
      const float* X = (const float*)Xv + (size_t)ar * 128 + kg * 8;
      #pragma unroll
      for (int ks = 0; ks < 4; ++ks) {
        float4 a = *(const float4*)(X + ks * 32);
        float4 b = *(const float4*)(X + ks * 32 + 4);
        union { u32 w[4]; bf16x8 v; } u;
        u.w[0] = (u32)f2bf(a.x) | ((u32)f2bf(a.y) << 16);
        u.w[1] = (u32)f2bf(a.z) | ((u32)f2bf(a.w) << 16);
        u.w[2] = (u32)f2bf(b.x) | ((u32)f2bf(b.y) << 16);
        u.w[3] = (u32)f2bf(b.z) | ((u32)f2bf(b.w) << 16);
        afrag[ks] = u.v;
      }
    } else {
      const u16* X = (const u16*)Xv + (size_t)ar * 128 + kg * 8;
      #pragma unroll
      for (int ks = 0; ks < 4; ++ks) afrag[ks] = *(const bf16x8*)(X + ks * 32);
    }
    int crow0 = chunk * 128 + wid * 16 + kg * 4;   // C/D: row=(lane>>4)*4+reg, col=lane&15
    float sc[4];
    #pragma unroll
    for (int j = 0; j < 4; ++j)
      sc[j] = (scale != nullptr && crow0 + j < NND) ? scale[crow0 + j] : 1.0f;
    #pragma unroll
    for (int t = 0; t < 8; ++t) {
      int coln = t * 16 + m16;
      f32x4 acc = {0.f, 0.f, 0.f, 0.f};
      #pragma unroll
      for (int ks = 0; ks < 4; ++ks) {
        int c8 = (ks * 4 + kg) ^ (coln & 7);
        bf16x8 bhf = *(const bf16x8*)(Bh + coln * 128 + c8 * 8);
        bf16x8 blf = *(const bf16x8*)(Bl + coln * 128 + c8 * 8);
        acc = __builtin_amdgcn_mfma_f32_16x16x32_bf16(afrag[ks], bhf, acc, 0, 0, 0);
        acc = __builtin_amdgcn_mfma_f32_16x16x32_bf16(afrag[ks], blf, acc, 0, 0, 0);
      }
      #pragma unroll
      for (int j = 0; j < 4; ++j) {
        int r = crow0 + j;
        if (r < NND) OUT[(size_t)r * ostride + ooff + coln] = f2bf(acc[j] * sc[j]);
      }
    }
  }
}

// ---------------- gather-aggregate: one NODE per wave64, 16 gathers in flight ----------
__global__ __launch_bounds__(256) void k_gather(const int* __restrict__ ptr, const uint2* __restrict__ sre,
                                                const float* __restrict__ dinv, const u16* __restrict__ Ts,
                                                u16* __restrict__ H, const float* __restrict__ bias) {
  int wid = threadIdx.x >> 6, lane = threadIdx.x & 63;
  int q = lane & 31, eo = lane >> 5;
  int v = blockIdx.x * 4 + wid; if (v >= NND) return;
  int p0 = ptr[v], p1 = ptr[v + 1];
  const uint2* T2 = (const uint2*)Ts;
  float4 acc = make_float4(0.f, 0.f, 0.f, 0.f);
  if (eo == 0) acc = unpack4(T2[(size_t)v * 32 + q]);   // self-loop (Ts pre-scaled by dinv[src])
  for (int j2 = p0; j2 < p1; j2 += 16) {
    bool ok[8]; int r[8];
    #pragma unroll
    for (int s = 0; s < 8; ++s) {
      int j = j2 + s * 2 + eo;
      ok[s] = j < p1;
      r[s] = (int)sre[ok[s] ? j : p0].x;
    }
    float4 m[8];
    #pragma unroll
    for (int s = 0; s < 8; ++s) m[s] = unpack4(T2[(size_t)r[s] * 32 + q]);
    #pragma unroll
    for (int s = 0; s < 8; ++s)
      if (ok[s]) { acc.x += m[s].x; acc.y += m[s].y; acc.z += m[s].z; acc.w += m[s].w; }
  }
  acc.x += __shfl_xor(acc.x, 32);
  acc.y += __shfl_xor(acc.y, 32);
  acc.z += __shfl_xor(acc.z, 32);
  acc.w += __shfl_xor(acc.w, 32);
  if (eo == 0) {
    float s = dinv[v];
    float4 b = ((const float4*)bias)[q];
    float o0 = fmaxf(fmaf(acc.x, s, b.x), 0.f);
    float o1 = fmaxf(fmaf(acc.y, s, b.y), 0.f);
    float o2 = fmaxf(fmaf(acc.z, s, b.z), 0.f);
    float o3 = fmaxf(fmaf(acc.w, s, b.w), 0.f);
    uint2 o;
    o.x = (u32)f2bf(o0) | ((u32)f2bf(o1) << 16);
    o.y = (u32)f2bf(o2) | ((u32)f2bf(o3) << 16);
    ((uint2*)H)[(size_t)v * 32 + q] = o;
  }
}

// ---------------- edge head: one NODE per wave64, 16 gathers in flight ----------------
// UV: [NND][256] bf16 (U = cols 0..127, V = cols 128..255)
__global__ __launch_bounds__(256) void k_edge(const int* __restrict__ ptr, const uint2* __restrict__ sre,
                                              const u16* __restrict__ UV,
                                              const float* __restrict__ be1, const float* __restrict__ We2,
                                              const float* __restrict__ be2, float* __restrict__ out) {
  int wid = threadIdx.x >> 6, lane = threadIdx.x & 63;
  int q = lane & 31, eo = lane >> 5;
  int c = blockIdx.x * 4 + wid; if (c >= NND) return;
  int p0 = ptr[c], p1 = ptr[c + 1];
  if (p0 == p1) return;
  const uint2* UV2 = (const uint2*)UV;
  float4 vv = unpack4(UV2[(size_t)c * 64 + 32 + q]);
  float4 b = ((const float4*)be1)[q];
  vv.x += b.x; vv.y += b.y; vv.z += b.z; vv.w += b.w;
  float4 w2 = ((const float4*)We2)[q];
  float bias2 = be2[0];
  for (int j2 = p0; j2 < p1; j2 += 16) {
    bool ok[8]; uint2 e[8];
    #pragma unroll
    for (int s = 0; s < 8; ++s) {
      int j = j2 + s * 2 + eo;
      ok[s] = j < p1;
      e[s] = sre[ok[s] ? j : p0];
    }
    float4 u[8];
    #pragma unroll
    for (int s = 0; s < 8; ++s) u[s] = unpack4(UV2[(size_t)e[s].x * 64 + q]);
    float p[8];
    #pragma unroll
    for (int s = 0; s < 8; ++s) {
      p[s] = fmaxf(u[s].x + vv.x, 0.f) * w2.x
           + fmaxf(u[s].y + vv.y, 0.f) * w2.y
           + fmaxf(u[s].z + vv.z, 0.f) * w2.z
           + fmaxf(u[s].w + vv.w, 0.f) * w2.w;
    }
    #pragma unroll
    for (int off = 16; off; off >>= 1) {
      #pragma unroll
      for (int s = 0; s < 8; ++s) p[s] += __shfl_xor(p[s], off);
    }
    if (q == 0) {
      #pragma unroll
      for (int s = 0; s < 8; ++s)
        if (ok[s]) out[e[s].y] = 1.f / (1.f + __expf(-(p[s] + bias2)));
    }
  }
}

extern "C" void kernel_launch(void* const* d_in, const int* in_sizes, int n_in,
                              void* d_out, int out_size, void* d_ws, size_t ws_size,
                              hipStream_t stream) {
  const float* x   = (const float*)d_in[0];
  const int*   ei  = (const int*)d_in[1];
  const float* W1  = (const float*)d_in[2];
  const float* b1  = (const float*)d_in[3];
  const float* W2  = (const float*)d_in[4];
  const float* b2  = (const float*)d_in[5];
  const float* We1 = (const float*)d_in[6];
  const float* be1 = (const float*)d_in[7];
  const float* We2 = (const float*)d_in[8];
  const float* be2 = (const float*)d_in[9];
  float* out = (float*)d_out;

  const int* row  = ei;
  const int* colp = ei + NE;

  // ws layout (u32 units):
  // ptr[0,50064) dinv[50064,100112) bhist[100112,100308) bbase[100308,100504) bcur[100504,100700)
  // recs[100704,1700704) sre[1700704,3300704)
  // t1h[3300704,+8192) t1l[3308896) t2h[3317088) t2l[3325280) teh[3333472,+16384) tel[3349856,+16384)
  // Ts[3366240,+3.2M) H[6566240,+3.2M) UV[9766240,+6.4M)  end 16166240
  if (ws_size < (size_t)16166240 * 4) return;
  int*   ptr    = (int*)d_ws;
  float* dinv   = (float*)d_ws + 50064;
  u32*   bhist  = (u32*)d_ws + 100112;
  u32*   bbase  = (u32*)d_ws + 100308;
  u32*   bcur   = (u32*)d_ws + 100504;
  uint2* recs   = (uint2*)((u32*)d_ws + 100704);
  uint2* sre    = (uint2*)((u32*)d_ws + 1700704);
  u16*   t1h    = (u16*)((u32*)d_ws + 3300704);
  u16*   t1l    = (u16*)((u32*)d_ws + 3308896);
  u16*   t2h    = (u16*)((u32*)d_ws + 3317088);
  u16*   t2l    = (u16*)((u32*)d_ws + 3325280);
  u16*   teh    = (u16*)((u32*)d_ws + 3333472);
  u16*   tel    = (u16*)((u32*)d_ws + 3349856);
  u16*   Ts     = (u16*)((u32*)d_ws + 3366240);
  u16*   H      = (u16*)((u32*)d_ws + 6566240);
  u16*   UV     = (u16*)((u32*)d_ws + 9766240);

  hipMemsetAsync(bhist, 0, NBK * sizeof(u32), stream);
  k_wprep<<<256, 256, 0, stream>>>(W1, W2, We1, t1h, t1l, t2h, t2l, teh, tel);
  k_hist <<<BINB, 256, 0, stream>>>(colp, bhist);
  k_bscan<<<1, 256, 0, stream>>>(bhist, bbase, bcur);
  k_bin  <<<BINB, 256, 0, stream>>>(row, colp, bcur, recs);
  k_fine <<<NBK, 256, 0, stream>>>(bhist, bbase, recs, sre, ptr, dinv);

  int node_grid = (NND + 3) / 4;      // one node per wave64, 4 waves/block

  // layer 1: Ts = bf16((x@W1)*dinv) ; H = relu(dinv*(Ts_self + gather) + b1)
  k_mm<true><<<196, 512, 0, stream>>>(x, t1h, t1l, Ts, dinv, 128, 0);
  k_gather<<<node_grid, 256, 0, stream>>>(ptr, sre, dinv, Ts, H, b1);

  // layer 2
  k_mm<false><<<196, 512, 0, stream>>>(H, t2h, t2l, Ts, dinv, 128, 0);
  k_gather<<<node_grid, 256, 0, stream>>>(ptr, sre, dinv, Ts, H, b2);

  // edge head: UV = H @ [We1_top | We1_bot], then per-edge
  k_mm<false><<<196, 512, 0, stream>>>(H, teh, tel, UV, nullptr, 256, 0);
  k_mm<false><<<196, 512, 0, stream>>>(H, teh + 128 * 128, tel + 128 * 128, UV, nullptr, 256, 128);
  k_edge<<<node_grid, 256, 0, stream>>>(ptr, sre, UV, be1, We2, be2, out);
}

// Round 9
// 199.488 us; speedup vs baseline: 15.5072x; 1.2254x over previous
//
#include <hip/hip_runtime.h>
#include <math.h>

#define NND 50000
#define HD  128
#define NE  800000
#define NBK 196          // buckets of 256 nodes: col>>8, max 195
#define BINB 391         // ceil(NE/2048)
#define NCH 391          // 50048/128 row chunks for k_mm

typedef unsigned short u16;
typedef unsigned int   u32;
typedef __attribute__((ext_vector_type(8))) short bf16x8;
typedef __attribute__((ext_vector_type(4))) float f32x4;

__device__ __forceinline__ float bf2f(u32 u) {
  union { u32 i; float f; } v; v.i = u << 16; return v.f;
}
__device__ __forceinline__ u16 f2bf(float f) {
  union { float f; u32 i; } v; v.f = f;
  return (u16)((v.i + 0x7FFFu + ((v.i >> 16) & 1u)) >> 16);
}
__device__ __forceinline__ void unpack8(uint4 m, float* f) {
  f[0] = bf2f(m.x & 0xFFFFu); f[1] = bf2f(m.x >> 16);
  f[2] = bf2f(m.y & 0xFFFFu); f[3] = bf2f(m.y >> 16);
  f[4] = bf2f(m.z & 0xFFFFu); f[5] = bf2f(m.z >> 16);
  f[6] = bf2f(m.w & 0xFFFFu); f[7] = bf2f(m.w >> 16);
}

// ---------------- fused: bucket histogram + weight prep ----------------
// blocks [0,BINB): histogram of col>>8. blocks [BINB,BINB+256): transposed bf16 hi/lo weights,
// LDS-swizzled layout: element (n,k) at u16-index n*128 + ((k>>3 ^ (n&7))<<3) + (k&7)
__global__ __launch_bounds__(256) void k_prep(const int* __restrict__ col, u32* __restrict__ bhist,
                                              const float* __restrict__ W1, const float* __restrict__ W2,
                                              const float* __restrict__ We1,
                                              u16* __restrict__ t1h, u16* __restrict__ t1l,
                                              u16* __restrict__ t2h, u16* __restrict__ t2l,
                                              u16* __restrict__ teh, u16* __restrict__ tel) {
  __shared__ u32 lh[NBK];
  int tid = threadIdx.x;
  if (blockIdx.x < BINB) {
    if (tid < NBK) lh[tid] = 0;
    __syncthreads();
    int e0 = blockIdx.x * 2048;
    #pragma unroll
    for (int s = 0; s < 8; ++s) {
      int e = e0 + s * 256 + tid;
      if (e < NE) atomicAdd(&lh[col[e] >> 8], 1u);
    }
    __syncthreads();
    if (tid < NBK && lh[tid]) atomicAdd(&bhist[tid], lh[tid]);
    return;
  }
  int idx = (blockIdx.x - BINB) * 256 + tid;   // 65536 total
  float w;
  u16 *dh, *dl;
  int j;
  if (idx < 16384) {
    j = idx; int n = j >> 7, k = j & 127;
    w = W1[k * 128 + n]; dh = t1h; dl = t1l;
  } else if (idx < 32768) {
    j = idx - 16384; int n = j >> 7, k = j & 127;
    w = W2[k * 128 + n]; dh = t2h; dl = t2l;
  } else {
    j = idx - 32768; int n = j >> 7, k = j & 127;
    w = (n < 128) ? We1[k * 128 + n] : We1[(128 + k) * 128 + (n - 128)];
    dh = teh; dl = tel;
  }
  int n = j >> 7, k = j & 127;
  int sidx = n * 128 + ((((k >> 3) ^ (n & 7))) << 3) + (k & 7);
  u16 hi = f2bf(w);
  float res = w - bf2f((u32)hi);
  dh[sidx] = hi;
  dl[sidx] = f2bf(res);
}

// ---------------- scan bucket counts -> bbase, bcur ----------------
__global__ __launch_bounds__(256) void k_bscan(const u32* __restrict__ bhist, u32* __restrict__ bbase,
                                               u32* __restrict__ bcur) {
  __shared__ u32 ws[4];
  int tid = threadIdx.x, lane = tid & 63, wid = tid >> 6;
  u32 d = (tid < NBK) ? bhist[tid] : 0;
  u32 x = d;
  #pragma unroll
  for (int off = 1; off < 64; off <<= 1) {
    u32 y = __shfl_up(x, off);
    if (lane >= off) x += y;
  }
  if (lane == 63) ws[wid] = x;
  __syncthreads();
  u32 woff = 0;
  for (int w = 0; w < wid; ++w) woff += ws[w];
  if (tid < NBK) { bbase[tid] = woff + x - d; bcur[tid] = woff + x - d; }
}

// ---------------- binning: block-aggregated contiguous reservations per bucket --------
// record: x = row | ((col&255)<<16), y = eid
__global__ __launch_bounds__(256) void k_bin(const int* __restrict__ row, const int* __restrict__ col,
                                             u32* __restrict__ bcur, uint2* __restrict__ recs) {
  __shared__ u32 lcount[NBK], lbase[NBK];
  int tid = threadIdx.x;
  if (tid < NBK) lcount[tid] = 0;
  __syncthreads();
  int e0 = blockIdx.x * 2048;
  u32 rank[8]; int cv[8];
  #pragma unroll
  for (int s = 0; s < 8; ++s) {
    int e = e0 + s * 256 + tid;
    if (e < NE) {
      cv[s] = col[e];
      rank[s] = atomicAdd(&lcount[cv[s] >> 8], 1u);
    }
  }
  __syncthreads();
  if (tid < NBK && lcount[tid]) lbase[tid] = atomicAdd(&bcur[tid], lcount[tid]);
  __syncthreads();
  #pragma unroll
  for (int s = 0; s < 8; ++s) {
    int e = e0 + s * 256 + tid;
    if (e < NE) {
      int c = cv[s];
      u32 slot = lbase[c >> 8] + rank[s];
      recs[slot] = make_uint2((u32)row[e] | (((u32)c & 255u) << 16), (u32)e);
    }
  }
}

// ---------------- fine sort within bucket; emits sre, ptr, dinv ----------------
__global__ __launch_bounds__(256) void k_fine(const u32* __restrict__ bhist, const u32* __restrict__ bbase,
                                              const uint2* __restrict__ recs, uint2* __restrict__ sre,
                                              int* __restrict__ ptr, float* __restrict__ dinv) {
  __shared__ u32 lh[256];
  __shared__ u32 ws[4];
  int b = blockIdx.x, tid = threadIdx.x, lane = tid & 63, wid = tid >> 6;
  u32 base = bbase[b], cnt = bhist[b];
  lh[tid] = 0;
  __syncthreads();
  for (u32 i = tid; i < cnt; i += 256) atomicAdd(&lh[(recs[base + i].x >> 16) & 255u], 1u);
  __syncthreads();
  u32 ci = lh[tid];
  u32 x = ci;
  #pragma unroll
  for (int off = 1; off < 64; off <<= 1) {
    u32 y = __shfl_up(x, off);
    if (lane >= off) x += y;
  }
  if (lane == 63) ws[wid] = x;
  __syncthreads();
  u32 woff = 0;
  for (int w = 0; w < wid; ++w) woff += ws[w];
  u32 excl = woff + x - ci;
  int node = b * 256 + tid;
  if (node <= NND) ptr[node] = (int)(base + excl);
  if (node < NND) dinv[node] = rsqrtf((float)(ci + 1));
  __syncthreads();
  lh[tid] = excl;                 // cursors
  __syncthreads();
  for (u32 i = tid; i < cnt; i += 256) {
    uint2 rec = recs[base + i];
    u32 r = atomicAdd(&lh[(rec.x >> 16) & 255u], 1u);
    sre[base + r] = make_uint2(rec.x & 0xFFFFu, rec.y);
  }
}

// ---------------- persistent-W MFMA GEMM, one 128-row chunk per block ----------------
// OUT[r][h*128+n] = bf16( (X[r][:] . Wt_h[n][:]) * (scale?scale[r]:1) ), h = blockIdx/NCH
__device__ __forceinline__ void mm_body(const void* Xv, bool afp32,
                                        const u16* Whi, const u16* Wlo,
                                        u16* OUT, const float* scale, int ostride) {
  __shared__ __align__(16) u16 Bh[128 * 128];   // 32 KB
  __shared__ __align__(16) u16 Bl[128 * 128];   // 32 KB
  int tid = threadIdx.x;
  int h = blockIdx.x / NCH;
  int chunk = blockIdx.x - h * NCH;
  Whi += (size_t)h * 128 * 128;
  Wlo += (size_t)h * 128 * 128;
  int ooff = h * 128;
  {
    const uint4* gh = (const uint4*)Whi;
    const uint4* gl = (const uint4*)Wlo;
    uint4* lh = (uint4*)Bh;
    uint4* ll = (uint4*)Bl;
    #pragma unroll
    for (int i = 0; i < 4; ++i) {
      lh[tid + i * 512] = gh[tid + i * 512];
      ll[tid + i * 512] = gl[tid + i * 512];
    }
  }
  __syncthreads();
  int wid = tid >> 6, lane = tid & 63;
  int m16 = lane & 15, kg = lane >> 4;
  int arow = chunk * 128 + wid * 16 + m16;
  int ar = (arow < NND) ? arow : NND - 1;        // clamp: garbage stays in unstored D rows
  bf16x8 afrag[4];
  if (afp32) {
    const float* X = (const float*)Xv + (size_t)ar * 128 + kg * 8;
    #pragma unroll
    for (int ks = 0; ks < 4; ++ks) {
      float4 a = *(const float4*)(X + ks * 32);
      float4 b = *(const float4*)(X + ks * 32 + 4);
      union { u32 w[4]; bf16x8 v; } u;
      u.w[0] = (u32)f2bf(a.x) | ((u32)f2bf(a.y) << 16);
      u.w[1] = (u32)f2bf(a.z) | ((u32)f2bf(a.w) << 16);
      u.w[2] = (u32)f2bf(b.x) | ((u32)f2bf(b.y) << 16);
      u.w[3] = (u32)f2bf(b.z) | ((u32)f2bf(b.w) << 16);
      afrag[ks] = u.v;
    }
  } else {
    const u16* X = (const u16*)Xv + (size_t)ar * 128 + kg * 8;
    #pragma unroll
    for (int ks = 0; ks < 4; ++ks) afrag[ks] = *(const bf16x8*)(X + ks * 32);
  }
  int crow0 = chunk * 128 + wid * 16 + kg * 4;   // C/D: row=(lane>>4)*4+reg, col=lane&15
  float sc[4];
  #pragma unroll
  for (int j = 0; j < 4; ++j)
    sc[j] = (scale != nullptr && crow0 + j < NND) ? scale[crow0 + j] : 1.0f;
  #pragma unroll
  for (int t = 0; t < 8; ++t) {
    int coln = t * 16 + m16;
    f32x4 acc = {0.f, 0.f, 0.f, 0.f};
    #pragma unroll
    for (int ks = 0; ks < 4; ++ks) {
      int c8 = (ks * 4 + kg) ^ (coln & 7);
      bf16x8 bhf = *(const bf16x8*)(Bh + coln * 128 + c8 * 8);
      bf16x8 blf = *(const bf16x8*)(Bl + coln * 128 + c8 * 8);
      acc = __builtin_amdgcn_mfma_f32_16x16x32_bf16(afrag[ks], bhf, acc, 0, 0, 0);
      acc = __builtin_amdgcn_mfma_f32_16x16x32_bf16(afrag[ks], blf, acc, 0, 0, 0);
    }
    #pragma unroll
    for (int j = 0; j < 4; ++j) {
      int r = crow0 + j;
      if (r < NND) OUT[(size_t)r * ostride + ooff + coln] = f2bf(acc[j] * sc[j]);
    }
  }
}

template<bool AFP32>
__global__ __launch_bounds__(512) void k_mm(const void* __restrict__ Xv,
                                            const u16* __restrict__ Whi, const u16* __restrict__ Wlo,
                                            u16* __restrict__ OUT, const float* __restrict__ scale,
                                            int ostride) {
  mm_body(Xv, AFP32, Whi, Wlo, OUT, scale, ostride);
}

// ---------------- gather-aggregate: one NODE per wave64, 16 lanes/edge x 8ch, 32 in flight ----
__global__ __launch_bounds__(256) void k_gather(const int* __restrict__ ptr, const uint2* __restrict__ sre,
                                                const float* __restrict__ dinv, const u16* __restrict__ Ts,
                                                u16* __restrict__ H, const float* __restrict__ bias) {
  int wid = threadIdx.x >> 6, lane = threadIdx.x & 63;
  int ch8 = lane & 15, slot = lane >> 4;
  int v = blockIdx.x * 4 + wid; if (v >= NND) return;
  int p0 = ptr[v], p1 = ptr[v + 1];
  const uint4* T4 = (const uint4*)Ts;            // row = 16 uint4
  float acc[8];
  if (slot == 0) {
    uint4 m = T4[(size_t)v * 16 + ch8];          // self-loop (Ts pre-scaled by dinv[src])
    unpack8(m, acc);
  } else {
    #pragma unroll
    for (int k = 0; k < 8; ++k) acc[k] = 0.f;
  }
  for (int j2 = p0; j2 < p1; j2 += 32) {
    bool ok[8]; int r[8];
    #pragma unroll
    for (int u = 0; u < 8; ++u) {
      int j = j2 + u * 4 + slot;
      ok[u] = j < p1;
      r[u] = (int)sre[ok[u] ? j : p0].x;
    }
    uint4 m[8];
    #pragma unroll
    for (int u = 0; u < 8; ++u) m[u] = T4[(size_t)r[u] * 16 + ch8];
    #pragma unroll
    for (int u = 0; u < 8; ++u) {
      if (ok[u]) {
        float f[8]; unpack8(m[u], f);
        #pragma unroll
        for (int k = 0; k < 8; ++k) acc[k] += f[k];
      }
    }
  }
  #pragma unroll
  for (int k = 0; k < 8; ++k) {
    acc[k] += __shfl_xor(acc[k], 16);
    acc[k] += __shfl_xor(acc[k], 32);
  }
  if (slot == 0) {
    float s = dinv[v];
    float4 ba = *(const float4*)(bias + ch8 * 8);
    float4 bb = *(const float4*)(bias + ch8 * 8 + 4);
    float bv[8] = {ba.x, ba.y, ba.z, ba.w, bb.x, bb.y, bb.z, bb.w};
    u32 pk[4];
    #pragma unroll
    for (int k = 0; k < 4; ++k) {
      float o0 = fmaxf(fmaf(acc[2 * k], s, bv[2 * k]), 0.f);
      float o1 = fmaxf(fmaf(acc[2 * k + 1], s, bv[2 * k + 1]), 0.f);
      pk[k] = (u32)f2bf(o0) | ((u32)f2bf(o1) << 16);
    }
    *(uint4*)(H + (size_t)v * 128 + ch8 * 8) = make_uint4(pk[0], pk[1], pk[2], pk[3]);
  }
}

// ---------------- edge head: one NODE per wave64, 16 lanes/edge x 8ch, 32 in flight -------
// UV: [NND][256] bf16 (U = cols 0..127, V = cols 128..255)
__global__ __launch_bounds__(256) void k_edge(const int* __restrict__ ptr, const uint2* __restrict__ sre,
                                              const u16* __restrict__ UV,
                                              const float* __restrict__ be1, const float* __restrict__ We2,
                                              const float* __restrict__ be2, float* __restrict__ out) {
  int wid = threadIdx.x >> 6, lane = threadIdx.x & 63;
  int ch8 = lane & 15, slot = lane >> 4;
  int c = blockIdx.x * 4 + wid; if (c >= NND) return;
  int p0 = ptr[c], p1 = ptr[c + 1];
  if (p0 == p1) return;
  const uint4* UV4 = (const uint4*)UV;           // row = 32 uint4
  float vv[8];
  {
    uint4 mv = UV4[(size_t)c * 32 + 16 + ch8];
    unpack8(mv, vv);
    float4 ba = *(const float4*)(be1 + ch8 * 8);
    float4 bb = *(const float4*)(be1 + ch8 * 8 + 4);
    vv[0] += ba.x; vv[1] += ba.y; vv[2] += ba.z; vv[3] += ba.w;
    vv[4] += bb.x; vv[5] += bb.y; vv[6] += bb.z; vv[7] += bb.w;
  }
  float w2[8];
  {
    float4 wa = *(const float4*)(We2 + ch8 * 8);
    float4 wb = *(const float4*)(We2 + ch8 * 8 + 4);
    w2[0] = wa.x; w2[1] = wa.y; w2[2] = wa.z; w2[3] = wa.w;
    w2[4] = wb.x; w2[5] = wb.y; w2[6] = wb.z; w2[7] = wb.w;
  }
  float bias2 = be2[0];
  for (int j2 = p0; j2 < p1; j2 += 32) {
    bool ok[8]; uint2 e[8];
    #pragma unroll
    for (int u = 0; u < 8; ++u) {
      int j = j2 + u * 4 + slot;
      ok[u] = j < p1;
      e[u] = sre[ok[u] ? j : p0];
    }
    uint4 m[8];
    #pragma unroll
    for (int u = 0; u < 8; ++u) m[u] = UV4[(size_t)e[u].x * 32 + ch8];
    float p[8];
    #pragma unroll
    for (int u = 0; u < 8; ++u) {
      float f[8]; unpack8(m[u], f);
      float s0 = fmaxf(f[0] + vv[0], 0.f) * w2[0] + fmaxf(f[1] + vv[1], 0.f) * w2[1];
      s0 += fmaxf(f[2] + vv[2], 0.f) * w2[2] + fmaxf(f[3] + vv[3], 0.f) * w2[3];
      s0 += fmaxf(f[4] + vv[4], 0.f) * w2[4] + fmaxf(f[5] + vv[5], 0.f) * w2[5];
      s0 += fmaxf(f[6] + vv[6], 0.f) * w2[6] + fmaxf(f[7] + vv[7], 0.f) * w2[7];
      p[u] = s0;
    }
    #pragma unroll
    for (int off = 8; off; off >>= 1) {
      #pragma unroll
      for (int u = 0; u < 8; ++u) p[u] += __shfl_xor(p[u], off);
    }
    if (ch8 == 0) {
      #pragma unroll
      for (int u = 0; u < 8; ++u)
        if (ok[u]) out[e[u].y] = 1.f / (1.f + __expf(-(p[u] + bias2)));
    }
  }
}

extern "C" void kernel_launch(void* const* d_in, const int* in_sizes, int n_in,
                              void* d_out, int out_size, void* d_ws, size_t ws_size,
                              hipStream_t stream) {
  const float* x   = (const float*)d_in[0];
  const int*   ei  = (const int*)d_in[1];
  const float* W1  = (const float*)d_in[2];
  const float* b1  = (const float*)d_in[3];
  const float* W2  = (const float*)d_in[4];
  const float* b2  = (const float*)d_in[5];
  const float* We1 = (const float*)d_in[6];
  const float* be1 = (const float*)d_in[7];
  const float* We2 = (const float*)d_in[8];
  const float* be2 = (const float*)d_in[9];
  float* out = (float*)d_out;

  const int* row  = ei;
  const int* colp = ei + NE;

  // ws layout (u32 units):
  // ptr[0,50064) dinv[50064,100112) bhist[100112,100308) bbase[100308,100504) bcur[100504,100700)
  // recs[100704,1700704) sre[1700704,3300704)
  // t1h[3300704,+8192) t1l[3308896) t2h[3317088) t2l[3325280) teh[3333472,+16384) tel[3349856,+16384)
  // Ts[3366240,+3.2M) H[6566240,+3.2M) UV[9766240,+6.4M)  end 16166240
  if (ws_size < (size_t)16166240 * 4) return;
  int*   ptr    = (int*)d_ws;
  float* dinv   = (float*)d_ws + 50064;
  u32*   bhist  = (u32*)d_ws + 100112;
  u32*   bbase  = (u32*)d_ws + 100308;
  u32*   bcur   = (u32*)d_ws + 100504;
  uint2* recs   = (uint2*)((u32*)d_ws + 100704);
  uint2* sre    = (uint2*)((u32*)d_ws + 1700704);
  u16*   t1h    = (u16*)((u32*)d_ws + 3300704);
  u16*   t1l    = (u16*)((u32*)d_ws + 3308896);
  u16*   t2h    = (u16*)((u32*)d_ws + 3317088);
  u16*   t2l    = (u16*)((u32*)d_ws + 3325280);
  u16*   teh    = (u16*)((u32*)d_ws + 3333472);
  u16*   tel    = (u16*)((u32*)d_ws + 3349856);
  u16*   Ts     = (u16*)((u32*)d_ws + 3366240);
  u16*   H      = (u16*)((u32*)d_ws + 6566240);
  u16*   UV     = (u16*)((u32*)d_ws + 9766240);

  (void)hipMemsetAsync(bhist, 0, NBK * sizeof(u32), stream);
  k_prep <<<BINB + 256, 256, 0, stream>>>(colp, bhist, W1, W2, We1, t1h, t1l, t2h, t2l, teh, tel);
  k_bscan<<<1, 256, 0, stream>>>(bhist, bbase, bcur);
  k_bin  <<<BINB, 256, 0, stream>>>(row, colp, bcur, recs);
  k_fine <<<NBK, 256, 0, stream>>>(bhist, bbase, recs, sre, ptr, dinv);

  int node_grid = (NND + 3) / 4;      // one node per wave64, 4 waves/block

  // layer 1: Ts = bf16((x@W1)*dinv) ; H = relu(dinv*(Ts_self + gather) + b1)
  k_mm<true><<<NCH, 512, 0, stream>>>(x, t1h, t1l, Ts, dinv, 128);
  k_gather<<<node_grid, 256, 0, stream>>>(ptr, sre, dinv, Ts, H, b1);

  // layer 2
  k_mm<false><<<NCH, 512, 0, stream>>>(H, t2h, t2l, Ts, dinv, 128);
  k_gather<<<node_grid, 256, 0, stream>>>(ptr, sre, dinv, Ts, H, b2);

  // edge head: UV = H @ [We1_top | We1_bot] in ONE dispatch (h = blockIdx/NCH), then per-edge
  k_mm<false><<<2 * NCH, 512, 0, stream>>>(H, teh, tel, UV, nullptr, 256);
  k_edge<<<node_grid, 256, 0, stream>>>(ptr, sre, UV, be1, We2, be2, out);
}